// Round 2
// baseline (799.909 us; speedup 1.0000x reference)
//
#include <hip/hip_runtime.h>
#include <stdint.h>
#include <math.h>

#define NTOK 16384
#define HID  2048
#define NGRP 16          // HID/128
#define EPSF 1e-5f

typedef __bf16 bf16;
typedef __bf16 bf16x8 __attribute__((ext_vector_type(8)));
typedef float  f32x4  __attribute__((ext_vector_type(4)));

// ---------------- helpers ----------------

__device__ __forceinline__ void async_load16(const void* g, void* l) {
  __builtin_amdgcn_global_load_lds((const __attribute__((address_space(1))) void*)g,
                                   (__attribute__((address_space(3))) void*)l, 16, 0, 0);
}

// bit-exact fp8 e4m3fn round-to-nearest-even; input must be pre-clipped to [-448,448]
__device__ __forceinline__ float fp8_e4m3_rne(float v) {
  float a = fabsf(v);
  float s = (v < 0.f) ? -1.f : 1.f;
  if (a < 0.015625f) {                 // below 2^-6: fp8 subnormal, quantum 2^-9
    float r = rintf(a * 512.0f);       // v_rndne = RNE
    return s * r * 0.001953125f;
  }
  uint32_t u = __float_as_uint(a);
  u = (u + 0x7FFFFu + ((u >> 20) & 1u)) & 0xFFF00000u;  // RNE to 3 mantissa bits
  return s * __uint_as_float(u);
}

__device__ __forceinline__ float block_sum256(float v) {
  __shared__ float sh[4];
  #pragma unroll
  for (int o = 32; o > 0; o >>= 1) v += __shfl_xor(v, o, 64);
  if ((threadIdx.x & 63) == 0) sh[threadIdx.x >> 6] = v;
  __syncthreads();
  return sh[0] + sh[1] + sh[2] + sh[3];
}

// ue8m0 scale: exp2(ceil(log2(max(amax,1e-10)/448))), emulating numpy fp32 semantics
__device__ __forceinline__ float ue8m0_scale(float amax) {
  float v = fmaxf(amax, 1e-10f) / 448.0f;
  float l = (float)log2((double)v);    // correctly-rounded; exact at powers of 2
  return exp2f(ceilf(l));
}

// ---------------- kernels ----------------

// w[z][k][n] f32 -> Wt[z][n][k] bf16, 64x64 tiles, vectorized both sides.
__global__ __launch_bounds__(256) void k_transpose_cast(const float* __restrict__ W,
                                                        bf16* __restrict__ Wt) {
  __shared__ float tile[64][65];
  const size_t mat = (size_t)HID * HID;
  const float* Wz = W + mat * blockIdx.z;
  bf16* Wtz = Wt + mat * blockIdx.z;
  int bn = blockIdx.x * 64;   // n base
  int bk = blockIdx.y * 64;   // k base
  int t = threadIdx.x;
  // load: tile[k][n] via float4, rows t>>4 (+16 per pass), cols (t&15)*4
  {
    int r = t >> 4, c = (t & 15) * 4;
    #pragma unroll
    for (int i = 0; i < 4; i++) {
      float4 v = *(const float4*)(Wz + (size_t)(bk + r + 16 * i) * HID + bn + c);
      tile[r + 16 * i][c] = v.x; tile[r + 16 * i][c + 1] = v.y;
      tile[r + 16 * i][c + 2] = v.z; tile[r + 16 * i][c + 3] = v.w;
    }
  }
  __syncthreads();
  // store: thread covers n = t>>2, k in [(t&3)*16, +16) -> two bf16x8 stores
  {
    int n = t >> 2, kc = (t & 3) * 16;
    bf16x8 o0, o1;
    #pragma unroll
    for (int j = 0; j < 8; j++) o0[j] = (bf16)tile[kc + j][n];
    #pragma unroll
    for (int j = 0; j < 8; j++) o1[j] = (bf16)tile[kc + 8 + j][n];
    bf16* dst = Wtz + (size_t)(bn + n) * HID + bk + kc;
    *(bf16x8*)dst = o0;
    *(bf16x8*)(dst + 8) = o1;
  }
}

// y = rmsnorm(relu(x)) * nw -> bf16 Y;  also write relu(x) -> bf16 R (residual).
// one block per row.
__global__ __launch_bounds__(256) void k_pre(const float* __restrict__ x,
                                             const float* __restrict__ nw,
                                             bf16* __restrict__ Y,
                                             bf16* __restrict__ R) {
  size_t base = (size_t)blockIdx.x * HID + threadIdx.x * 8;
  float4 v0 = *(const float4*)(x + base);
  float4 v1 = *(const float4*)(x + base + 4);
  float z[8] = {v0.x, v0.y, v0.z, v0.w, v1.x, v1.y, v1.z, v1.w};
  float ss = 0.f;
  #pragma unroll
  for (int i = 0; i < 8; i++) { z[i] = fmaxf(z[i], 0.f); ss += z[i] * z[i]; }
  float tot = block_sum256(ss);
  float s = rsqrtf(tot * (1.0f / HID) + EPSF);
  bf16x8 rr;
  #pragma unroll
  for (int i = 0; i < 8; i++) rr[i] = (bf16)z[i];
  *(bf16x8*)(R + base) = rr;
  int j0 = threadIdx.x * 8;
  float4 w0 = *(const float4*)(nw + j0);
  float4 w1 = *(const float4*)(nw + j0 + 4);
  float wv[8] = {w0.x, w0.y, w0.z, w0.w, w1.x, w1.y, w1.z, w1.w};
  bf16x8 o;
  #pragma unroll
  for (int i = 0; i < 8; i++) o[i] = (bf16)(z[i] * s * wv[i]);
  *(bf16x8*)(Y + base) = o;
}

// resid = residIn + Cin ; y = rmsnorm(resid)*nw ; per-128-group ue8m0 quant
// -> Aout (bf16 of fp8 values), scaleOut; residOut (bf16, may alias residIn).
// one block per row; thread t covers cols [t*8, t*8+8); group g = t>>4.
__global__ __launch_bounds__(256) void k_fuse_quant(const bf16* __restrict__ residIn,
                                                    const bf16* __restrict__ Cin,
                                                    const float* __restrict__ nw,
                                                    bf16* __restrict__ residOut,
                                                    bf16* __restrict__ Aout,
                                                    float* __restrict__ scaleOut) {
  int row = blockIdx.x;
  int j0 = threadIdx.x * 8;
  size_t base = (size_t)row * HID + j0;
  bf16x8 c  = *(const bf16x8*)(Cin + base);
  bf16x8 rv = *(const bf16x8*)(residIn + base);
  float r[8]; float ss = 0.f;
  #pragma unroll
  for (int i = 0; i < 8; i++) { r[i] = (float)rv[i] + (float)c[i]; ss += r[i] * r[i]; }
  float tot = block_sum256(ss);
  float s = rsqrtf(tot * (1.0f / HID) + EPSF);

  bf16x8 ro;
  #pragma unroll
  for (int i = 0; i < 8; i++) ro[i] = (bf16)r[i];
  *(bf16x8*)(residOut + base) = ro;

  float4 w0 = *(const float4*)(nw + j0);
  float4 w1 = *(const float4*)(nw + j0 + 4);
  float wv[8] = {w0.x, w0.y, w0.z, w0.w, w1.x, w1.y, w1.z, w1.w};
  float y[8], amax = 0.f;
  #pragma unroll
  for (int i = 0; i < 8; i++) { y[i] = r[i] * s * wv[i]; amax = fmaxf(amax, fabsf(y[i])); }
  // group = 128 cols = 16 consecutive threads (within one wave)
  amax = fmaxf(amax, __shfl_xor(amax, 1, 64));
  amax = fmaxf(amax, __shfl_xor(amax, 2, 64));
  amax = fmaxf(amax, __shfl_xor(amax, 4, 64));
  amax = fmaxf(amax, __shfl_xor(amax, 8, 64));
  float scale = ue8m0_scale(amax);
  float inv = 1.0f / scale;          // exact: scale is a power of 2
  bf16x8 q;
  #pragma unroll
  for (int i = 0; i < 8; i++) {
    float t = fminf(fmaxf(y[i] * inv, -448.f), 448.f);
    q[i] = (bf16)fp8_e4m3_rne(t);    // fp8 values are exact in bf16
  }
  *(bf16x8*)(Aout + base) = q;
  if ((threadIdx.x & 15) == 0) scaleOut[(size_t)row * NGRP + (j0 >> 7)] = scale;
}

// y4 = rmsnorm(residIn + Cin) * nw -> f32 out.  one block per row.
__global__ __launch_bounds__(256) void k_final(const bf16* __restrict__ residIn,
                                               const bf16* __restrict__ Cin,
                                               const float* __restrict__ nw,
                                               float* __restrict__ out) {
  size_t base = (size_t)blockIdx.x * HID + threadIdx.x * 8;
  bf16x8 c  = *(const bf16x8*)(Cin + base);
  bf16x8 rv = *(const bf16x8*)(residIn + base);
  float r[8]; float ss = 0.f;
  #pragma unroll
  for (int i = 0; i < 8; i++) { r[i] = (float)rv[i] + (float)c[i]; ss += r[i] * r[i]; }
  float tot = block_sum256(ss);
  float s = rsqrtf(tot * (1.0f / HID) + EPSF);
  int j0 = threadIdx.x * 8;
  float4 w0 = *(const float4*)(nw + j0);
  float4 w1 = *(const float4*)(nw + j0 + 4);
  float wv[8] = {w0.x, w0.y, w0.z, w0.w, w1.x, w1.y, w1.z, w1.w};
  float4 o0, o1;
  o0.x = r[0]*s*wv[0]; o0.y = r[1]*s*wv[1]; o0.z = r[2]*s*wv[2]; o0.w = r[3]*s*wv[3];
  o1.x = r[4]*s*wv[4]; o1.y = r[5]*s*wv[5]; o1.z = r[6]*s*wv[6]; o1.w = r[7]*s*wv[7];
  *(float4*)(out + base) = o0;
  *(float4*)(out + base + 4) = o1;
}

// C[M][N] = A[M][K] * B^T[N][K], bf16 in, fp32 acc, bf16 out.
// 256x256 tile, BK=32, 8 waves (2Mx4N), 4-slot LDS ring (128 KiB), staging 3
// K-tiles ahead via global_load_lds w16, counted s_waitcnt vmcnt(8) (never 0
// in-loop), raw s_barrier.
// KEY (round 2): fragment ds_reads are software-pipelined ONE PHASE AHEAD.
// Each phase issues reads whose consumer is the NEXT MFMA cluster, so the
// compiler's dependency-driven lgkmcnt waits are counted (4 or 8), and the
// LDS pipe drains the in-flight reads WHILE the MFMA pipe runs -> pipe overlap.
// Per tile: phase0 {stage t+3; read A-half1; vmcnt(8); barrier; 16 MFMA Q0 on
// prev-read frags}; phase1 {read tile t+1 B+A-half0; 16 MFMA Q1; barrier}.
// Swizzle: 16B chunk c of row r stored at slot c^((r>>1)&3) (pre-swizzled
// global source, same XOR on read) -> 2-way bank sharing only (free).
// Grid: bn = blockIdx&7 pins each XCD to one 256-col B panel (L2-resident).
__global__ __launch_bounds__(512, 2) void k_gemm(const bf16* __restrict__ A,
                                                 const bf16* __restrict__ B,
                                                 bf16* __restrict__ C,
                                                 int M, int N, int K) {
  // slot layout: slot*32768 | A: [0,16384) B: [16384,32768)
  // within A/B: row r (0..255) at r*64 bytes; chunk slots of 16 B XOR-swizzled
  __shared__ __align__(16) char lds[4 * 32768];
  int b = blockIdx.x;
  int bn = b & 7;            // XCD-local column panel
  int bm = b >> 3;
  int tid = threadIdx.x;
  int wave = tid >> 6, lane = tid & 63;
  int q = lane >> 4, rr = lane & 15;
  int wm = wave >> 2, wn = wave & 3;      // 2 x 4 wave grid, per-wave 128x64

  // staging source pointers (pre-swizzled): thread covers linear LDS chunk
  // m = i*512 + tid -> row r = m>>2, source chunk c = (m&3) ^ ((r>>1)&3)
  const bf16* aSrc[2]; const bf16* bSrc[2];
  #pragma unroll
  for (int i = 0; i < 2; i++) {
    int m = i * 512 + tid;
    int r = m >> 2;
    int c = (m & 3) ^ ((r >> 1) & 3);
    aSrc[i] = A + (size_t)(bm * 256 + r) * K + c * 8;
    bSrc[i] = B + (size_t)(bn * 256 + r) * K + c * 8;
  }

  // per-lane LDS read offset: row rr (within 16-row frag), k-chunk q, swizzled
  const int swz = (rr >> 1) & 3;
  const int ldoff = rr * 64 + ((q ^ swz) << 4);

  f32x4 acc[8][4];
  #pragma unroll
  for (int mf = 0; mf < 8; mf++)
    #pragma unroll
    for (int nf = 0; nf < 4; nf++)
      #pragma unroll
      for (int e = 0; e < 4; e++) acc[mf][nf][e] = 0.f;

  const int NT = K / 32;     // 64 K-tiles (even)

  // prologue: stage tiles 0,1,2 into slots 0,1,2 (4 loads each: A0,A1,B0,B1)
  #pragma unroll
  for (int t = 0; t < 3; ++t) {
    char* db = lds + t * 32768 + wave * 1024;
    async_load16(aSrc[0] + t * 32, db);
    async_load16(aSrc[1] + t * 32, db + 8192);
    async_load16(bSrc[0] + t * 32, db + 16384);
    async_load16(bSrc[1] + t * 32, db + 16384 + 8192);
  }
  asm volatile("s_waitcnt vmcnt(8)" ::: "memory");   // tile 0 landed
  asm volatile("s_barrier" ::: "memory");

  // initial fragment reads: tile 0, B all + A half0
  bf16x8 fA[4], fB[4], gA[4], gB[4];
  {
    const char* rbA = lds + wm * 8192 + ldoff;
    const char* rbB = lds + 16384 + wn * 4096 + ldoff;
    #pragma unroll
    for (int nf = 0; nf < 4; nf++) fB[nf] = *(const bf16x8*)(rbB + nf * 1024);
    #pragma unroll
    for (int mf = 0; mf < 4; mf++) fA[mf] = *(const bf16x8*)(rbA + mf * 1024);
  }

#define TILE_BODY(T, CA, CB, NA, NB)                                           \
  {                                                                            \
    const int t_ = (T);                                                        \
    const char* sb_  = lds + (t_ & 3) * 32768;                                 \
    const char* rbA_ = sb_ + wm * 8192 + ldoff;                                \
    const int u_ = (t_ + 3 < NT) ? (t_ + 3) : (NT - 1);                        \
    char* ub_ = lds + ((t_ + 3) & 3) * 32768 + wave * 1024;                    \
    /* phase 0: stage t+3, read A-half1 (for Q1), MFMA Q0 on prev frags */     \
    async_load16(aSrc[0] + u_ * 32, ub_);                                      \
    async_load16(aSrc[1] + u_ * 32, ub_ + 8192);                               \
    async_load16(bSrc[0] + u_ * 32, ub_ + 16384);                              \
    async_load16(bSrc[1] + u_ * 32, ub_ + 16384 + 8192);                       \
    bf16x8 a1_[4];                                                             \
    _Pragma("unroll")                                                          \
    for (int mf = 0; mf < 4; mf++)                                             \
      a1_[mf] = *(const bf16x8*)(rbA_ + 4096 + mf * 1024);                     \
    asm volatile("s_waitcnt vmcnt(8)" ::: "memory");  /* tile t+1 landed */    \
    asm volatile("s_barrier" ::: "memory");                                    \
    __builtin_amdgcn_s_setprio(1);                                             \
    _Pragma("unroll")                                                          \
    for (int mf = 0; mf < 4; mf++)                                             \
      _Pragma("unroll")                                                        \
      for (int nf = 0; nf < 4; nf++)                                           \
        acc[mf][nf] = __builtin_amdgcn_mfma_f32_16x16x32_bf16(CA[mf], CB[nf],  \
                                                       acc[mf][nf], 0, 0, 0);  \
    __builtin_amdgcn_s_setprio(0);                                             \
    /* phase 1: read tile t+1 frags (for next tile's Q0), MFMA Q1 */           \
    const char* nb_  = lds + ((t_ + 1) & 3) * 32768;                           \
    const char* nAp_ = nb_ + wm * 8192 + ldoff;                                \
    const char* nBp_ = nb_ + 16384 + wn * 4096 + ldoff;                        \
    _Pragma("unroll")                                                          \
    for (int nf = 0; nf < 4; nf++) NB[nf] = *(const bf16x8*)(nBp_ + nf * 1024);\
    _Pragma("unroll")                                                          \
    for (int mf = 0; mf < 4; mf++) NA[mf] = *(const bf16x8*)(nAp_ + mf * 1024);\
    __builtin_amdgcn_s_setprio(1);                                             \
    _Pragma("unroll")                                                          \
    for (int mf = 0; mf < 4; mf++)                                             \
      _Pragma("unroll")                                                        \
      for (int nf = 0; nf < 4; nf++)                                           \
        acc[4 + mf][nf] = __builtin_amdgcn_mfma_f32_16x16x32_bf16(a1_[mf],     \
                                            CB[nf], acc[4 + mf][nf], 0, 0, 0); \
    __builtin_amdgcn_s_setprio(0);                                             \
    asm volatile("s_barrier" ::: "memory");                                    \
  }

  for (int t = 0; t < NT; t += 2) {
    TILE_BODY(t,     fA, fB, gA, gB)
    TILE_BODY(t + 1, gA, gB, fA, fB)
  }
#undef TILE_BODY

  // drain trailing (dead) stages before block exit / LDS reuse
  asm volatile("s_waitcnt vmcnt(0)" ::: "memory");

  // epilogue: C/D layout col=lane&15, row=(lane>>4)*4+reg
  #pragma unroll
  for (int mf = 0; mf < 8; mf++)
    #pragma unroll
    for (int nf = 0; nf < 4; nf++)
      #pragma unroll
      for (int tt = 0; tt < 4; tt++) {
        int rowi = bm * 256 + wm * 128 + mf * 16 + q * 4 + tt;
        int coli = bn * 256 + wn * 64 + nf * 16 + rr;
        C[(size_t)rowi * N + coli] = (bf16)acc[mf][nf][tt];
      }
}

// ---------------- launch ----------------

extern "C" void kernel_launch(void* const* d_in, const int* in_sizes, int n_in,
                              void* d_out, int out_size, void* d_ws, size_t ws_size,
                              hipStream_t stream) {
  const float* x      = (const float*)d_in[0];
  const float* norm_w = (const float*)d_in[1];
  const float* w      = (const float*)d_in[2];

  float* out   = (float*)d_out;
  float* y4o   = out;
  float* s2o   = out + (size_t)NTOK * HID;           // y2_s [16384,16]
  float* s3o   = s2o + (size_t)NTOK * NGRP;          // y3_s [16384,16]

  char* ws = (char*)d_ws;
  const size_t WT_B = (size_t)3 * HID * HID * 2;     // 25,165,824
  const size_t AB_B = (size_t)NTOK * HID * 2;        // 67,108,864
  bf16* Wt   = (bf16*)ws;
  bf16* Abuf = (bf16*)(ws + WT_B);
  bf16* Cbuf = (bf16*)(ws + WT_B + AB_B);
  bf16* Rbuf = (bf16*)(ws + WT_B + 2 * AB_B);
  const size_t MATE = (size_t)HID * HID;

  dim3 gT(HID / 64, HID / 64, 3);
  int  gG = (NTOK / 256) * (HID / 256);    // 512 blocks, bn = b&7 (XCD panel)

  k_transpose_cast<<<gT, 256, 0, stream>>>(w, Wt);
  k_pre<<<NTOK, 256, 0, stream>>>(x, norm_w, Abuf, Rbuf);
  k_gemm<<<gG, 512, 0, stream>>>(Abuf, Wt, Cbuf, NTOK, HID, HID);
  k_fuse_quant<<<NTOK, 256, 0, stream>>>(Rbuf, Cbuf, norm_w + HID, Rbuf, Abuf, s2o);
  k_gemm<<<gG, 512, 0, stream>>>(Abuf, Wt + MATE, Cbuf, NTOK, HID, HID);
  k_fuse_quant<<<NTOK, 256, 0, stream>>>(Rbuf, Cbuf, norm_w + 2 * HID, Rbuf, Abuf, s3o);
  k_gemm<<<gG, 512, 0, stream>>>(Abuf, Wt + 2 * MATE, Cbuf, NTOK, HID, HID);
  k_final<<<NTOK, 256, 0, stream>>>(Rbuf, Cbuf, norm_w + 3 * HID, y4o);
}

// Round 3
// 778.242 us; speedup vs baseline: 1.0278x; 1.0278x over previous
//
#include <hip/hip_runtime.h>
#include <stdint.h>
#include <math.h>

#define NTOK 16384
#define HID  2048
#define NGRP 16          // HID/128
#define EPSF 1e-5f

typedef __bf16 bf16;
typedef __bf16 bf16x8 __attribute__((ext_vector_type(8)));
typedef float  f32x4  __attribute__((ext_vector_type(4)));

// ---------------- helpers ----------------

__device__ __forceinline__ void async_load16(const void* g, void* l) {
  __builtin_amdgcn_global_load_lds((const __attribute__((address_space(1))) void*)g,
                                   (__attribute__((address_space(3))) void*)l, 16, 0, 0);
}

// bit-exact fp8 e4m3fn round-to-nearest-even; input must be pre-clipped to [-448,448]
__device__ __forceinline__ float fp8_e4m3_rne(float v) {
  float a = fabsf(v);
  float s = (v < 0.f) ? -1.f : 1.f;
  if (a < 0.015625f) {                 // below 2^-6: fp8 subnormal, quantum 2^-9
    float r = rintf(a * 512.0f);       // v_rndne = RNE
    return s * r * 0.001953125f;
  }
  uint32_t u = __float_as_uint(a);
  u = (u + 0x7FFFFu + ((u >> 20) & 1u)) & 0xFFF00000u;  // RNE to 3 mantissa bits
  return s * __uint_as_float(u);
}

__device__ __forceinline__ float block_sum256(float v) {
  __shared__ float sh[4];
  #pragma unroll
  for (int o = 32; o > 0; o >>= 1) v += __shfl_xor(v, o, 64);
  if ((threadIdx.x & 63) == 0) sh[threadIdx.x >> 6] = v;
  __syncthreads();
  return sh[0] + sh[1] + sh[2] + sh[3];
}

// ue8m0 scale: exp2(ceil(log2(max(amax,1e-10)/448))), emulating numpy fp32 semantics
__device__ __forceinline__ float ue8m0_scale(float amax) {
  float v = fmaxf(amax, 1e-10f) / 448.0f;
  float l = (float)log2((double)v);    // correctly-rounded; exact at powers of 2
  return exp2f(ceilf(l));
}

// ---------------- kernels ----------------

// w[z][k][n] f32 -> Wt[z][n][k] bf16, 64x64 tiles, vectorized both sides.
__global__ __launch_bounds__(256) void k_transpose_cast(const float* __restrict__ W,
                                                        bf16* __restrict__ Wt) {
  __shared__ float tile[64][65];
  const size_t mat = (size_t)HID * HID;
  const float* Wz = W + mat * blockIdx.z;
  bf16* Wtz = Wt + mat * blockIdx.z;
  int bn = blockIdx.x * 64;   // n base
  int bk = blockIdx.y * 64;   // k base
  int t = threadIdx.x;
  // load: tile[k][n] via float4, rows t>>4 (+16 per pass), cols (t&15)*4
  {
    int r = t >> 4, c = (t & 15) * 4;
    #pragma unroll
    for (int i = 0; i < 4; i++) {
      float4 v = *(const float4*)(Wz + (size_t)(bk + r + 16 * i) * HID + bn + c);
      tile[r + 16 * i][c] = v.x; tile[r + 16 * i][c + 1] = v.y;
      tile[r + 16 * i][c + 2] = v.z; tile[r + 16 * i][c + 3] = v.w;
    }
  }
  __syncthreads();
  // store: thread covers n = t>>2, k in [(t&3)*16, +16) -> two bf16x8 stores
  {
    int n = t >> 2, kc = (t & 3) * 16;
    bf16x8 o0, o1;
    #pragma unroll
    for (int j = 0; j < 8; j++) o0[j] = (bf16)tile[kc + j][n];
    #pragma unroll
    for (int j = 0; j < 8; j++) o1[j] = (bf16)tile[kc + 8 + j][n];
    bf16* dst = Wtz + (size_t)(bn + n) * HID + bk + kc;
    *(bf16x8*)dst = o0;
    *(bf16x8*)(dst + 8) = o1;
  }
}

// y = rmsnorm(relu(x)) * nw -> bf16 Y;  also write relu(x) -> bf16 R (residual).
// one block per row.
__global__ __launch_bounds__(256) void k_pre(const float* __restrict__ x,
                                             const float* __restrict__ nw,
                                             bf16* __restrict__ Y,
                                             bf16* __restrict__ R) {
  size_t base = (size_t)blockIdx.x * HID + threadIdx.x * 8;
  float4 v0 = *(const float4*)(x + base);
  float4 v1 = *(const float4*)(x + base + 4);
  float z[8] = {v0.x, v0.y, v0.z, v0.w, v1.x, v1.y, v1.z, v1.w};
  float ss = 0.f;
  #pragma unroll
  for (int i = 0; i < 8; i++) { z[i] = fmaxf(z[i], 0.f); ss += z[i] * z[i]; }
  float tot = block_sum256(ss);
  float s = rsqrtf(tot * (1.0f / HID) + EPSF);
  bf16x8 rr;
  #pragma unroll
  for (int i = 0; i < 8; i++) rr[i] = (bf16)z[i];
  *(bf16x8*)(R + base) = rr;
  int j0 = threadIdx.x * 8;
  float4 w0 = *(const float4*)(nw + j0);
  float4 w1 = *(const float4*)(nw + j0 + 4);
  float wv[8] = {w0.x, w0.y, w0.z, w0.w, w1.x, w1.y, w1.z, w1.w};
  bf16x8 o;
  #pragma unroll
  for (int i = 0; i < 8; i++) o[i] = (bf16)(z[i] * s * wv[i]);
  *(bf16x8*)(Y + base) = o;
}

// resid = residIn + Cin ; y = rmsnorm(resid)*nw ; per-128-group ue8m0 quant
// -> Aout (bf16 of fp8 values), scaleOut; residOut (bf16, may alias residIn).
// one block per row; thread t covers cols [t*8, t*8+8); group g = t>>4.
__global__ __launch_bounds__(256) void k_fuse_quant(const bf16* __restrict__ residIn,
                                                    const bf16* __restrict__ Cin,
                                                    const float* __restrict__ nw,
                                                    bf16* __restrict__ residOut,
                                                    bf16* __restrict__ Aout,
                                                    float* __restrict__ scaleOut) {
  int row = blockIdx.x;
  int j0 = threadIdx.x * 8;
  size_t base = (size_t)row * HID + j0;
  bf16x8 c  = *(const bf16x8*)(Cin + base);
  bf16x8 rv = *(const bf16x8*)(residIn + base);
  float r[8]; float ss = 0.f;
  #pragma unroll
  for (int i = 0; i < 8; i++) { r[i] = (float)rv[i] + (float)c[i]; ss += r[i] * r[i]; }
  float tot = block_sum256(ss);
  float s = rsqrtf(tot * (1.0f / HID) + EPSF);

  bf16x8 ro;
  #pragma unroll
  for (int i = 0; i < 8; i++) ro[i] = (bf16)r[i];
  *(bf16x8*)(residOut + base) = ro;

  float4 w0 = *(const float4*)(nw + j0);
  float4 w1 = *(const float4*)(nw + j0 + 4);
  float wv[8] = {w0.x, w0.y, w0.z, w0.w, w1.x, w1.y, w1.z, w1.w};
  float y[8], amax = 0.f;
  #pragma unroll
  for (int i = 0; i < 8; i++) { y[i] = r[i] * s * wv[i]; amax = fmaxf(amax, fabsf(y[i])); }
  // group = 128 cols = 16 consecutive threads (within one wave)
  amax = fmaxf(amax, __shfl_xor(amax, 1, 64));
  amax = fmaxf(amax, __shfl_xor(amax, 2, 64));
  amax = fmaxf(amax, __shfl_xor(amax, 4, 64));
  amax = fmaxf(amax, __shfl_xor(amax, 8, 64));
  float scale = ue8m0_scale(amax);
  float inv = 1.0f / scale;          // exact: scale is a power of 2
  bf16x8 q;
  #pragma unroll
  for (int i = 0; i < 8; i++) {
    float t = fminf(fmaxf(y[i] * inv, -448.f), 448.f);
    q[i] = (bf16)fp8_e4m3_rne(t);    // fp8 values are exact in bf16
  }
  *(bf16x8*)(Aout + base) = q;
  if ((threadIdx.x & 15) == 0) scaleOut[(size_t)row * NGRP + (j0 >> 7)] = scale;
}

// y4 = rmsnorm(residIn + Cin) * nw -> f32 out.  one block per row.
__global__ __launch_bounds__(256) void k_final(const bf16* __restrict__ residIn,
                                               const bf16* __restrict__ Cin,
                                               const float* __restrict__ nw,
                                               float* __restrict__ out) {
  size_t base = (size_t)blockIdx.x * HID + threadIdx.x * 8;
  bf16x8 c  = *(const bf16x8*)(Cin + base);
  bf16x8 rv = *(const bf16x8*)(residIn + base);
  float r[8]; float ss = 0.f;
  #pragma unroll
  for (int i = 0; i < 8; i++) { r[i] = (float)rv[i] + (float)c[i]; ss += r[i] * r[i]; }
  float tot = block_sum256(ss);
  float s = rsqrtf(tot * (1.0f / HID) + EPSF);
  int j0 = threadIdx.x * 8;
  float4 w0 = *(const float4*)(nw + j0);
  float4 w1 = *(const float4*)(nw + j0 + 4);
  float wv[8] = {w0.x, w0.y, w0.z, w0.w, w1.x, w1.y, w1.z, w1.w};
  float4 o0, o1;
  o0.x = r[0]*s*wv[0]; o0.y = r[1]*s*wv[1]; o0.z = r[2]*s*wv[2]; o0.w = r[3]*s*wv[3];
  o1.x = r[4]*s*wv[4]; o1.y = r[5]*s*wv[5]; o1.z = r[6]*s*wv[6]; o1.w = r[7]*s*wv[7];
  *(float4*)(out + base) = o0;
  *(float4*)(out + base + 4) = o1;
}

// C[M][N] = A[M][K] * B^T[N][K], bf16 in, fp32 acc, bf16 out.
// 256x256 tile, BK=32, 8 waves (2Mx4N), 4-slot LDS ring (128 KiB), staging 3
// K-tiles ahead via global_load_lds w16, counted s_waitcnt vmcnt(8) (never 0
// in-loop), raw s_barrier, s_setprio around MFMA clusters.
// Round-3 change: L2-locality block mapping. HW round-robins blockIdx across
// XCDs (xcd = b&7). Old map (bn=b&7) made every XCD stream ALL 64 MB of A
// cold (FETCH_SIZE 270 MB vs 72 MB unique inputs -> staged A-loads at HBM
// latency -> vmcnt stall dominates). New map: x=b&7, j=b>>3,
//   bm = 8x + (j&7), bn = j>>3
// Per XCD: 32 concurrent blocks span 8 A-panels (each co-staged by 4
// temporally-aligned blocks, L2/MSHR-merged) and 4 B-panels (4 MB = L2-sized,
// each shared by 8 blocks). Staged loads become L2 hits; 3-tile prefetch
// covers the latency fully.
// Swizzle: 16B chunk c of row r stored at slot c^((r>>1)&3) (pre-swizzled
// global source, same XOR on read) -> 2-way bank sharing only (free).
__global__ __launch_bounds__(512, 2) void k_gemm(const bf16* __restrict__ A,
                                                 const bf16* __restrict__ B,
                                                 bf16* __restrict__ C,
                                                 int M, int N, int K) {
  // slot layout: slot*32768 | A: [0,16384) B: [16384,32768)
  // within A/B: row r (0..255) at r*64 bytes; chunk slots of 16 B XOR-swizzled
  __shared__ __align__(16) char lds[4 * 32768];
  int b = blockIdx.x;
  int x = b & 7, j = b >> 3;
  int bm = x * 8 + (j & 7);   // A-panel: 8 per XCD, co-staged by 4 aligned blocks
  int bn = j >> 3;            // B-panel: 4 concurrent per XCD (4 MB, L2-resident)
  int tid = threadIdx.x;
  int wave = tid >> 6, lane = tid & 63;
  int q = lane >> 4, rr = lane & 15;
  int wm = wave >> 2, wn = wave & 3;      // 2 x 4 wave grid, per-wave 128x64

  // staging source pointers (pre-swizzled): thread covers linear LDS chunk
  // m = i*512 + tid -> row r = m>>2, source chunk c = (m&3) ^ ((r>>1)&3)
  const bf16* aSrc[2]; const bf16* bSrc[2];
  #pragma unroll
  for (int i = 0; i < 2; i++) {
    int m = i * 512 + tid;
    int r = m >> 2;
    int c = (m & 3) ^ ((r >> 1) & 3);
    aSrc[i] = A + (size_t)(bm * 256 + r) * K + c * 8;
    bSrc[i] = B + (size_t)(bn * 256 + r) * K + c * 8;
  }

  // per-lane LDS read offset: row rr (within 16-row frag), k-chunk q, swizzled
  const int swz = (rr >> 1) & 3;
  const int ldoff = rr * 64 + ((q ^ swz) << 4);

  f32x4 acc[8][4];
  #pragma unroll
  for (int mf = 0; mf < 8; mf++)
    #pragma unroll
    for (int nf = 0; nf < 4; nf++)
      #pragma unroll
      for (int e = 0; e < 4; e++) acc[mf][nf][e] = 0.f;

  const int NT = K / 32;     // 64 K-tiles

  // prologue: stage tiles 0,1,2 into slots 0,1,2 (4 loads each: A0,A1,B0,B1)
  #pragma unroll
  for (int t = 0; t < 3; ++t) {
    char* db = lds + t * 32768 + wave * 1024;
    async_load16(aSrc[0] + t * 32, db);
    async_load16(aSrc[1] + t * 32, db + 8192);
    async_load16(bSrc[0] + t * 32, db + 16384);
    async_load16(bSrc[1] + t * 32, db + 16384 + 8192);
  }
  asm volatile("s_waitcnt vmcnt(8)" ::: "memory");   // tile 0 landed
  asm volatile("s_barrier" ::: "memory");

  for (int t = 0; t < NT; ++t) {
    const char* sb  = lds + (t & 3) * 32768;
    const char* rbA = sb + wm * 8192 + ldoff;            // wm*128 rows
    const char* rbB = sb + 16384 + wn * 4096 + ldoff;    // wn*64 rows
    const int u  = (t + 3 < NT) ? (t + 3) : (NT - 1);    // clamped: tail stages
    char* ub = lds + ((t + 3) & 3) * 32768 + wave * 1024;// land in dead slots

    // ---- phase 0: read B(all) + A(half 0); stage A(t+3); MFMA quadrant 0 ----
    bf16x8 bfr[4], afr[4];
    #pragma unroll
    for (int nf = 0; nf < 4; nf++)
      bfr[nf] = *(const bf16x8*)(rbB + nf * 1024);
    #pragma unroll
    for (int mf = 0; mf < 4; mf++)
      afr[mf] = *(const bf16x8*)(rbA + mf * 1024);
    async_load16(aSrc[0] + u * 32, ub);
    async_load16(aSrc[1] + u * 32, ub + 8192);
    asm volatile("s_barrier" ::: "memory");
    __builtin_amdgcn_s_setprio(1);
    #pragma unroll
    for (int mf = 0; mf < 4; mf++)
      #pragma unroll
      for (int nf = 0; nf < 4; nf++)
        acc[mf][nf] = __builtin_amdgcn_mfma_f32_16x16x32_bf16(afr[mf], bfr[nf], acc[mf][nf], 0, 0, 0);
    __builtin_amdgcn_s_setprio(0);
    asm volatile("s_barrier" ::: "memory");

    // ---- phase 1: read A(half 1); stage B(t+3); MFMA quadrant 1 ----
    #pragma unroll
    for (int mf = 0; mf < 4; mf++)
      afr[mf] = *(const bf16x8*)(rbA + 4096 + mf * 1024);
    async_load16(bSrc[0] + u * 32, ub + 16384);
    async_load16(bSrc[1] + u * 32, ub + 16384 + 8192);
    asm volatile("s_barrier" ::: "memory");
    __builtin_amdgcn_s_setprio(1);
    #pragma unroll
    for (int mf = 0; mf < 4; mf++)
      #pragma unroll
      for (int nf = 0; nf < 4; nf++)
        acc[4 + mf][nf] = __builtin_amdgcn_mfma_f32_16x16x32_bf16(afr[mf], bfr[nf], acc[4 + mf][nf], 0, 0, 0);
    __builtin_amdgcn_s_setprio(0);
    // checkpoint: allow tiles t+2,t+3 (8 loads) in flight; guarantees t+1 landed
    asm volatile("s_waitcnt vmcnt(8)" ::: "memory");
    asm volatile("s_barrier" ::: "memory");
  }

  // drain trailing (dead) stages before block exit / LDS reuse
  asm volatile("s_waitcnt vmcnt(0)" ::: "memory");

  // epilogue: C/D layout col=lane&15, row=(lane>>4)*4+reg
  #pragma unroll
  for (int mf = 0; mf < 8; mf++)
    #pragma unroll
    for (int nf = 0; nf < 4; nf++)
      #pragma unroll
      for (int tt = 0; tt < 4; tt++) {
        int rowi = bm * 256 + wm * 128 + mf * 16 + q * 4 + tt;
        int coli = bn * 256 + wn * 64 + nf * 16 + rr;
        C[(size_t)rowi * N + coli] = (bf16)acc[mf][nf][tt];
      }
}

// ---------------- launch ----------------

extern "C" void kernel_launch(void* const* d_in, const int* in_sizes, int n_in,
                              void* d_out, int out_size, void* d_ws, size_t ws_size,
                              hipStream_t stream) {
  const float* x      = (const float*)d_in[0];
  const float* norm_w = (const float*)d_in[1];
  const float* w      = (const float*)d_in[2];

  float* out   = (float*)d_out;
  float* y4o   = out;
  float* s2o   = out + (size_t)NTOK * HID;           // y2_s [16384,16]
  float* s3o   = s2o + (size_t)NTOK * NGRP;          // y3_s [16384,16]

  char* ws = (char*)d_ws;
  const size_t WT_B = (size_t)3 * HID * HID * 2;     // 25,165,824
  const size_t AB_B = (size_t)NTOK * HID * 2;        // 67,108,864
  bf16* Wt   = (bf16*)ws;
  bf16* Abuf = (bf16*)(ws + WT_B);
  bf16* Cbuf = (bf16*)(ws + WT_B + AB_B);
  bf16* Rbuf = (bf16*)(ws + WT_B + 2 * AB_B);
  const size_t MATE = (size_t)HID * HID;

  dim3 gT(HID / 64, HID / 64, 3);
  int  gG = (NTOK / 256) * (HID / 256);    // 512 blocks; in-kernel XCD mapping

  k_transpose_cast<<<gT, 256, 0, stream>>>(w, Wt);
  k_pre<<<NTOK, 256, 0, stream>>>(x, norm_w, Abuf, Rbuf);
  k_gemm<<<gG, 512, 0, stream>>>(Abuf, Wt, Cbuf, NTOK, HID, HID);
  k_fuse_quant<<<NTOK, 256, 0, stream>>>(Rbuf, Cbuf, norm_w + HID, Rbuf, Abuf, s2o);
  k_gemm<<<gG, 512, 0, stream>>>(Abuf, Wt + MATE, Cbuf, NTOK, HID, HID);
  k_fuse_quant<<<NTOK, 256, 0, stream>>>(Rbuf, Cbuf, norm_w + 2 * HID, Rbuf, Abuf, s3o);
  k_gemm<<<gG, 512, 0, stream>>>(Abuf, Wt + 2 * MATE, Cbuf, NTOK, HID, HID);
  k_final<<<NTOK, 256, 0, stream>>>(Rbuf, Cbuf, norm_w + 3 * HID, y4o);
}

// Round 4
// 729.111 us; speedup vs baseline: 1.0971x; 1.0674x over previous
//
#include <hip/hip_runtime.h>
#include <stdint.h>
#include <math.h>

#define NTOK 16384
#define HID  2048
#define NGRP 16          // HID/128
#define EPSF 1e-5f

typedef __bf16 bf16;
typedef __bf16 bf16x8 __attribute__((ext_vector_type(8)));
typedef float  f32x4  __attribute__((ext_vector_type(4)));

// ---------------- helpers ----------------

__device__ __forceinline__ void async_load16(const void* g, void* l) {
  __builtin_amdgcn_global_load_lds((const __attribute__((address_space(1))) void*)g,
                                   (__attribute__((address_space(3))) void*)l, 16, 0, 0);
}

// bit-exact fp8 e4m3fn round-to-nearest-even; input must be pre-clipped to [-448,448]
__device__ __forceinline__ float fp8_e4m3_rne(float v) {
  float a = fabsf(v);
  float s = (v < 0.f) ? -1.f : 1.f;
  if (a < 0.015625f) {                 // below 2^-6: fp8 subnormal, quantum 2^-9
    float r = rintf(a * 512.0f);       // v_rndne = RNE
    return s * r * 0.001953125f;
  }
  uint32_t u = __float_as_uint(a);
  u = (u + 0x7FFFFu + ((u >> 20) & 1u)) & 0xFFF00000u;  // RNE to 3 mantissa bits
  return s * __uint_as_float(u);
}

__device__ __forceinline__ float block_sum256(float v) {
  __shared__ float sh[4];
  #pragma unroll
  for (int o = 32; o > 0; o >>= 1) v += __shfl_xor(v, o, 64);
  if ((threadIdx.x & 63) == 0) sh[threadIdx.x >> 6] = v;
  __syncthreads();
  return sh[0] + sh[1] + sh[2] + sh[3];
}

// ue8m0 scale: exp2(ceil(log2(max(amax,1e-10)/448))), emulating numpy fp32 semantics
__device__ __forceinline__ float ue8m0_scale(float amax) {
  float v = fmaxf(amax, 1e-10f) / 448.0f;
  float l = (float)log2((double)v);    // correctly-rounded; exact at powers of 2
  return exp2f(ceilf(l));
}

// ---------------- kernels ----------------

// w[z][k][n] f32 -> Wt[z][n][k] bf16, 64x64 tiles, vectorized both sides.
__global__ __launch_bounds__(256) void k_transpose_cast(const float* __restrict__ W,
                                                        bf16* __restrict__ Wt) {
  __shared__ float tile[64][65];
  const size_t mat = (size_t)HID * HID;
  const float* Wz = W + mat * blockIdx.z;
  bf16* Wtz = Wt + mat * blockIdx.z;
  int bn = blockIdx.x * 64;   // n base
  int bk = blockIdx.y * 64;   // k base
  int t = threadIdx.x;
  {
    int r = t >> 4, c = (t & 15) * 4;
    #pragma unroll
    for (int i = 0; i < 4; i++) {
      float4 v = *(const float4*)(Wz + (size_t)(bk + r + 16 * i) * HID + bn + c);
      tile[r + 16 * i][c] = v.x; tile[r + 16 * i][c + 1] = v.y;
      tile[r + 16 * i][c + 2] = v.z; tile[r + 16 * i][c + 3] = v.w;
    }
  }
  __syncthreads();
  {
    int n = t >> 2, kc = (t & 3) * 16;
    bf16x8 o0, o1;
    #pragma unroll
    for (int j = 0; j < 8; j++) o0[j] = (bf16)tile[kc + j][n];
    #pragma unroll
    for (int j = 0; j < 8; j++) o1[j] = (bf16)tile[kc + 8 + j][n];
    bf16* dst = Wtz + (size_t)(bn + n) * HID + bk + kc;
    *(bf16x8*)dst = o0;
    *(bf16x8*)(dst + 8) = o1;
  }
}

// y = rmsnorm(relu(x)) * nw -> bf16 Y;  also write relu(x) -> bf16 R (residual).
__global__ __launch_bounds__(256) void k_pre(const float* __restrict__ x,
                                             const float* __restrict__ nw,
                                             bf16* __restrict__ Y,
                                             bf16* __restrict__ R) {
  size_t base = (size_t)blockIdx.x * HID + threadIdx.x * 8;
  float4 v0 = *(const float4*)(x + base);
  float4 v1 = *(const float4*)(x + base + 4);
  float z[8] = {v0.x, v0.y, v0.z, v0.w, v1.x, v1.y, v1.z, v1.w};
  float ss = 0.f;
  #pragma unroll
  for (int i = 0; i < 8; i++) { z[i] = fmaxf(z[i], 0.f); ss += z[i] * z[i]; }
  float tot = block_sum256(ss);
  float s = rsqrtf(tot * (1.0f / HID) + EPSF);
  bf16x8 rr;
  #pragma unroll
  for (int i = 0; i < 8; i++) rr[i] = (bf16)z[i];
  *(bf16x8*)(R + base) = rr;
  int j0 = threadIdx.x * 8;
  float4 w0 = *(const float4*)(nw + j0);
  float4 w1 = *(const float4*)(nw + j0 + 4);
  float wv[8] = {w0.x, w0.y, w0.z, w0.w, w1.x, w1.y, w1.z, w1.w};
  bf16x8 o;
  #pragma unroll
  for (int i = 0; i < 8; i++) o[i] = (bf16)(z[i] * s * wv[i]);
  *(bf16x8*)(Y + base) = o;
}

// resid = residIn + Cin ; y = rmsnorm(resid)*nw ; per-128-group ue8m0 quant
__global__ __launch_bounds__(256) void k_fuse_quant(const bf16* __restrict__ residIn,
                                                    const bf16* __restrict__ Cin,
                                                    const float* __restrict__ nw,
                                                    bf16* __restrict__ residOut,
                                                    bf16* __restrict__ Aout,
                                                    float* __restrict__ scaleOut) {
  int row = blockIdx.x;
  int j0 = threadIdx.x * 8;
  size_t base = (size_t)row * HID + j0;
  bf16x8 c  = *(const bf16x8*)(Cin + base);
  bf16x8 rv = *(const bf16x8*)(residIn + base);
  float r[8]; float ss = 0.f;
  #pragma unroll
  for (int i = 0; i < 8; i++) { r[i] = (float)rv[i] + (float)c[i]; ss += r[i] * r[i]; }
  float tot = block_sum256(ss);
  float s = rsqrtf(tot * (1.0f / HID) + EPSF);

  bf16x8 ro;
  #pragma unroll
  for (int i = 0; i < 8; i++) ro[i] = (bf16)r[i];
  *(bf16x8*)(residOut + base) = ro;

  float4 w0 = *(const float4*)(nw + j0);
  float4 w1 = *(const float4*)(nw + j0 + 4);
  float wv[8] = {w0.x, w0.y, w0.z, w0.w, w1.x, w1.y, w1.z, w1.w};
  float y[8], amax = 0.f;
  #pragma unroll
  for (int i = 0; i < 8; i++) { y[i] = r[i] * s * wv[i]; amax = fmaxf(amax, fabsf(y[i])); }
  amax = fmaxf(amax, __shfl_xor(amax, 1, 64));
  amax = fmaxf(amax, __shfl_xor(amax, 2, 64));
  amax = fmaxf(amax, __shfl_xor(amax, 4, 64));
  amax = fmaxf(amax, __shfl_xor(amax, 8, 64));
  float scale = ue8m0_scale(amax);
  float inv = 1.0f / scale;          // exact: scale is a power of 2
  bf16x8 q;
  #pragma unroll
  for (int i = 0; i < 8; i++) {
    float t = fminf(fmaxf(y[i] * inv, -448.f), 448.f);
    q[i] = (bf16)fp8_e4m3_rne(t);    // fp8 values are exact in bf16
  }
  *(bf16x8*)(Aout + base) = q;
  if ((threadIdx.x & 15) == 0) scaleOut[(size_t)row * NGRP + (j0 >> 7)] = scale;
}

// y4 = rmsnorm(residIn + Cin) * nw -> f32 out.
__global__ __launch_bounds__(256) void k_final(const bf16* __restrict__ residIn,
                                               const bf16* __restrict__ Cin,
                                               const float* __restrict__ nw,
                                               float* __restrict__ out) {
  size_t base = (size_t)blockIdx.x * HID + threadIdx.x * 8;
  bf16x8 c  = *(const bf16x8*)(Cin + base);
  bf16x8 rv = *(const bf16x8*)(residIn + base);
  float r[8]; float ss = 0.f;
  #pragma unroll
  for (int i = 0; i < 8; i++) { r[i] = (float)rv[i] + (float)c[i]; ss += r[i] * r[i]; }
  float tot = block_sum256(ss);
  float s = rsqrtf(tot * (1.0f / HID) + EPSF);
  int j0 = threadIdx.x * 8;
  float4 w0 = *(const float4*)(nw + j0);
  float4 w1 = *(const float4*)(nw + j0 + 4);
  float wv[8] = {w0.x, w0.y, w0.z, w0.w, w1.x, w1.y, w1.z, w1.w};
  float4 o0, o1;
  o0.x = r[0]*s*wv[0]; o0.y = r[1]*s*wv[1]; o0.z = r[2]*s*wv[2]; o0.w = r[3]*s*wv[3];
  o1.x = r[4]*s*wv[4]; o1.y = r[5]*s*wv[5]; o1.z = r[6]*s*wv[6]; o1.w = r[7]*s*wv[7];
  *(float4*)(out + base) = o0;
  *(float4*)(out + base + 4) = o1;
}

// C[M][N] = A[M][K] * B^T[N][K], bf16 in, fp32 acc, bf16 out.
// m201-faithful 8-phase schedule: 256x256 tile, BK=64, 8 waves (2Mx4N),
// 2 LDS buffers (128 KiB), 4 MFMA-phases per K-tile (quadrants Q00,Q01,Q10,Q11),
// per phase: {counted ds-reads (12/4/8/0) ; 1 half-tile stage (2 global_load_lds)
// ; s_barrier ; setprio(1) ; 16 MFMA ; setprio(0) ; s_barrier}.
// vmcnt(4) ONCE per K-tile at ph3 (never 0 in-loop): issue-order audit shows
// next tile's last half (A1, issued ph1) is guaranteed once only the 2 stages
// issued after it (ph2,ph3 = 4 vmem instrs) remain outstanding.
// Stage targets land only in dead LDS regions:
//   ph0: A-h0(t+1)->other buf (dead since t-1 ph2)   ph1: A-h1(t+1)->other
//   ph2: B-h0(t+2)->this buf (dead since ph1)        ph3: B-h1(t+2)->this
// Swizzle: rows are 128 B; physical 16B-chunk pc = lc ^ (row&7) (pre-swizzled
// global source since global_load_lds writes linearly; same XOR on ds_read)
// -> each 16-lane group spreads over all 8 chunks = 2 lanes/bank-quad = free.
// Grid map (round 3, kept): x=b&7, j=b>>3, bm=8x+(j&7), bn=j>>3 -> per-XCD
// L2-resident B panels; FETCH_SIZE 98 MB (was 270).
__global__ __launch_bounds__(512, 2) void k_gemm(const bf16* __restrict__ A,
                                                 const bf16* __restrict__ B,
                                                 bf16* __restrict__ C,
                                                 int M, int N, int K) {
  // buffer layout (64 KiB each, 2 buffers):
  //   A: [0,32768)  rows 0..255 * 128 B   (h0 = rows 0-127, h1 = 128-255)
  //   B: [32768,65536) same
  __shared__ __align__(16) char lds[2 * 65536];
  int b = blockIdx.x;
  int x = b & 7, j = b >> 3;
  int bm = x * 8 + (j & 7);
  int bn = j >> 3;
  int tid = threadIdx.x;
  int wave = tid >> 6, lane = tid & 63;
  int q = lane >> 4, rr = lane & 15;
  int wm = wave >> 2, wn = wave & 3;      // 2 x 4 wave grid, per-wave 128x64

  // staging source pointers (pre-swizzled). Per half-tile (128 rows x 64 bf16
  // = 16 KiB = 1024 chunks of 16 B), thread covers chunks m = ic*512 + tid:
  //   local row lr = m>>3, physical chunk cl = m&7, logical src chunk
  //   lc = cl ^ (lr&7). Dest (linear) = region + m*16 = region + ic*8192+tid*16.
  const bf16* aS[2][2]; const bf16* bS[2][2];   // [half][ic]
  #pragma unroll
  for (int ic = 0; ic < 2; ic++) {
    int m = ic * 512 + tid;
    int lr = m >> 3, cl = m & 7, lc = cl ^ (lr & 7);
    #pragma unroll
    for (int h = 0; h < 2; h++) {
      aS[h][ic] = A + (size_t)(bm * 256 + h * 128 + lr) * K + lc * 8;
      bS[h][ic] = B + (size_t)(bn * 256 + h * 128 + lr) * K + lc * 8;
    }
  }

  const int NT = K / 64;                  // 32 K-tiles
  const int pc0 = (q ^ (rr & 7)) << 4;    // swizzled chunk byte-offset, k-slot 0
  // k-slot 1: pc0 ^ 64

#define STAGE_A(h, tt) {                                                       \
    int ts_ = (tt) < NT ? (tt) : (NT - 1);                                     \
    char* d_ = lds + (((tt) & 1) * 65536) + (h) * 16384 + tid * 16;            \
    async_load16(aS[h][0] + (size_t)ts_ * 64, d_);                             \
    async_load16(aS[h][1] + (size_t)ts_ * 64, d_ + 8192); }
#define STAGE_B(h, tt) {                                                       \
    int ts_ = (tt) < NT ? (tt) : (NT - 1);                                     \
    char* d_ = lds + (((tt) & 1) * 65536) + 32768 + (h) * 16384 + tid * 16;    \
    async_load16(bS[h][0] + (size_t)ts_ * 64, d_);                             \
    async_load16(bS[h][1] + (size_t)ts_ * 64, d_ + 8192); }

  f32x4 acc[8][4];
  #pragma unroll
  for (int mf = 0; mf < 8; mf++)
    #pragma unroll
    for (int nf = 0; nf < 4; nf++)
      #pragma unroll
      for (int e = 0; e < 4; e++) acc[mf][nf][e] = 0.f;

  // prologue: tile0 {B0,B1,A0,A1}, tile1 {B0,B1}; wait tile0 (newest 2 stages
  // = 4 vmem instrs may remain), barrier.
  STAGE_B(0, 0) STAGE_B(1, 0) STAGE_A(0, 0) STAGE_A(1, 0)
  STAGE_B(0, 1) STAGE_B(1, 1)
  asm volatile("s_waitcnt vmcnt(4)" ::: "memory");
  asm volatile("s_barrier" ::: "memory");

#define MFMA8(AF, BF, MO, NO)                                                  \
    __builtin_amdgcn_s_setprio(1);                                             \
    _Pragma("unroll")                                                          \
    for (int s = 0; s < 2; s++)                                                \
      _Pragma("unroll")                                                        \
      for (int f = 0; f < 4; f++)                                              \
        _Pragma("unroll")                                                      \
        for (int n2 = 0; n2 < 2; n2++)                                         \
          acc[(MO) + f][(NO) + n2] = __builtin_amdgcn_mfma_f32_16x16x32_bf16(  \
              AF[f][s], BF[n2][s], acc[(MO) + f][(NO) + n2], 0, 0, 0);         \
    __builtin_amdgcn_s_setprio(0);

#define TILE(tau, XB) {                                                        \
    const char* Ax_ = lds + (XB) + wm * 16384;                                 \
    const char* Bx_ = lds + (XB) + 32768 + wn * 8192;                          \
    bf16x8 a0_[4][2], a1_[4][2], b0_[2][2], b1_[2][2];                         \
    /* ---- ph0: read A-i0(8)+B-j0(4); stage A0(t+1); MFMA Q00 ---- */         \
    _Pragma("unroll")                                                          \
    for (int f = 0; f < 4; f++)                                                \
      _Pragma("unroll")                                                        \
      for (int s = 0; s < 2; s++)                                              \
        a0_[f][s] = *(const bf16x8*)(Ax_ + f * 2048 + rr * 128 +               \
                                     (pc0 ^ (s << 6)));                        \
    _Pragma("unroll")                                                          \
    for (int n2 = 0; n2 < 2; n2++)                                             \
      _Pragma("unroll")                                                        \
      for (int s = 0; s < 2; s++)                                              \
        b0_[n2][s] = *(const bf16x8*)(Bx_ + n2 * 2048 + rr * 128 +             \
                                      (pc0 ^ (s << 6)));                       \
    STAGE_A(0, (tau) + 1)                                                      \
    asm volatile("s_barrier" ::: "memory");                                    \
    MFMA8(a0_, b0_, 0, 0)                                                      \
    asm volatile("s_barrier" ::: "memory");                                    \
    /* ---- ph1: read B-j1(4); stage A1(t+1); MFMA Q01 ---- */                 \
    _Pragma("unroll")                                                          \
    for (int n2 = 0; n2 < 2; n2++)                                             \
      _Pragma("unroll")                                                        \
      for (int s = 0; s < 2; s++)                                              \
        b1_[n2][s] = *(const bf16x8*)(Bx_ + 4096 + n2 * 2048 + rr * 128 +      \
                                      (pc0 ^ (s << 6)));                       \
    STAGE_A(1, (tau) + 1)                                                      \
    asm volatile("s_barrier" ::: "memory");                                    \
    MFMA8(a0_, b1_, 0, 2)                                                      \
    asm volatile("s_barrier" ::: "memory");                                    \
    /* ---- ph2: read A-i1(8); stage B0(t+2); MFMA Q10 ---- */                 \
    _Pragma("unroll")                                                          \
    for (int f = 0; f < 4; f++)                                                \
      _Pragma("unroll")                                                        \
      for (int s = 0; s < 2; s++)                                              \
        a1_[f][s] = *(const bf16x8*)(Ax_ + 8192 + f * 2048 + rr * 128 +        \
                                     (pc0 ^ (s << 6)));                        \
    STAGE_B(0, (tau) + 2)                                                      \
    asm volatile("s_barrier" ::: "memory");                                    \
    MFMA8(a1_, b0_, 4, 0)                                                      \
    asm volatile("s_barrier" ::: "memory");                                    \
    /* ---- ph3: stage B1(t+2); vmcnt(4) (tile t+1 landed); MFMA Q11 ---- */   \
    STAGE_B(1, (tau) + 2)                                                      \
    asm volatile("s_waitcnt vmcnt(4)" ::: "memory");                           \
    asm volatile("s_barrier" ::: "memory");                                    \
    MFMA8(a1_, b1_, 4, 2)                                                      \
    asm volatile("s_barrier" ::: "memory");                                    \
  }

  for (int tt = 0; tt < NT; tt += 2) {
    TILE(tt, 0)
    TILE(tt + 1, 65536)
  }
#undef TILE
#undef MFMA8
#undef STAGE_A
#undef STAGE_B

  // drain trailing (clamped/dead) stages
  asm volatile("s_waitcnt vmcnt(0)" ::: "memory");

  // epilogue: C/D layout col=lane&15, row=(lane>>4)*4+reg
  #pragma unroll
  for (int mf = 0; mf < 8; mf++)
    #pragma unroll
    for (int nf = 0; nf < 4; nf++)
      #pragma unroll
      for (int tt = 0; tt < 4; tt++) {
        int rowi = bm * 256 + wm * 128 + mf * 16 + q * 4 + tt;
        int coli = bn * 256 + wn * 64 + nf * 16 + rr;
        C[(size_t)rowi * N + coli] = (bf16)acc[mf][nf][tt];
      }
}

// ---------------- launch ----------------

extern "C" void kernel_launch(void* const* d_in, const int* in_sizes, int n_in,
                              void* d_out, int out_size, void* d_ws, size_t ws_size,
                              hipStream_t stream) {
  const float* x      = (const float*)d_in[0];
  const float* norm_w = (const float*)d_in[1];
  const float* w      = (const float*)d_in[2];

  float* out   = (float*)d_out;
  float* y4o   = out;
  float* s2o   = out + (size_t)NTOK * HID;           // y2_s [16384,16]
  float* s3o   = s2o + (size_t)NTOK * NGRP;          // y3_s [16384,16]

  char* ws = (char*)d_ws;
  const size_t WT_B = (size_t)3 * HID * HID * 2;     // 25,165,824
  const size_t AB_B = (size_t)NTOK * HID * 2;        // 67,108,864
  bf16* Wt   = (bf16*)ws;
  bf16* Abuf = (bf16*)(ws + WT_B);
  bf16* Cbuf = (bf16*)(ws + WT_B + AB_B);
  bf16* Rbuf = (bf16*)(ws + WT_B + 2 * AB_B);
  const size_t MATE = (size_t)HID * HID;

  dim3 gT(HID / 64, HID / 64, 3);
  int  gG = (NTOK / 256) * (HID / 256);    // 512 blocks; in-kernel XCD mapping

  k_transpose_cast<<<gT, 256, 0, stream>>>(w, Wt);
  k_pre<<<NTOK, 256, 0, stream>>>(x, norm_w, Abuf, Rbuf);
  k_gemm<<<gG, 512, 0, stream>>>(Abuf, Wt, Cbuf, NTOK, HID, HID);
  k_fuse_quant<<<NTOK, 256, 0, stream>>>(Rbuf, Cbuf, norm_w + HID, Rbuf, Abuf, s2o);
  k_gemm<<<gG, 512, 0, stream>>>(Abuf, Wt + MATE, Cbuf, NTOK, HID, HID);
  k_fuse_quant<<<NTOK, 256, 0, stream>>>(Rbuf, Cbuf, norm_w + 2 * HID, Rbuf, Abuf, s3o);
  k_gemm<<<gG, 512, 0, stream>>>(Abuf, Wt + 2 * MATE, Cbuf, NTOK, HID, HID);
  k_final<<<NTOK, 256, 0, stream>>>(Rbuf, Cbuf, norm_w + 3 * HID, y4o);
}

// Round 5
// 702.216 us; speedup vs baseline: 1.1391x; 1.0383x over previous
//
#include <hip/hip_runtime.h>
#include <stdint.h>
#include <math.h>

#define NTOK 16384
#define HID  2048
#define NGRP 16          // HID/128
#define EPSF 1e-5f

typedef __bf16 bf16;
typedef __bf16 bf16x8 __attribute__((ext_vector_type(8)));
typedef float  f32x4  __attribute__((ext_vector_type(4)));

// ---------------- helpers ----------------

__device__ __forceinline__ void async_load16(const void* g, void* l) {
  __builtin_amdgcn_global_load_lds((const __attribute__((address_space(1))) void*)g,
                                   (__attribute__((address_space(3))) void*)l, 16, 0, 0);
}

// bit-exact fp8 e4m3fn round-to-nearest-even; input must be pre-clipped to [-448,448]
__device__ __forceinline__ float fp8_e4m3_rne(float v) {
  float a = fabsf(v);
  float s = (v < 0.f) ? -1.f : 1.f;
  if (a < 0.015625f) {                 // below 2^-6: fp8 subnormal, quantum 2^-9
    float r = rintf(a * 512.0f);       // v_rndne = RNE
    return s * r * 0.001953125f;
  }
  uint32_t u = __float_as_uint(a);
  u = (u + 0x7FFFFu + ((u >> 20) & 1u)) & 0xFFF00000u;  // RNE to 3 mantissa bits
  return s * __uint_as_float(u);
}

__device__ __forceinline__ float block_sum256(float v) {
  __shared__ float sh[4];
  #pragma unroll
  for (int o = 32; o > 0; o >>= 1) v += __shfl_xor(v, o, 64);
  if ((threadIdx.x & 63) == 0) sh[threadIdx.x >> 6] = v;
  __syncthreads();
  return sh[0] + sh[1] + sh[2] + sh[3];
}

// ue8m0 scale: exp2(ceil(log2(max(amax,1e-10)/448))), emulating numpy fp32 semantics
__device__ __forceinline__ float ue8m0_scale(float amax) {
  float v = fmaxf(amax, 1e-10f) / 448.0f;
  float l = (float)log2((double)v);    // correctly-rounded; exact at powers of 2
  return exp2f(ceilf(l));
}

// ---------------- kernels ----------------

// w[z][k][n] f32 -> Wt[z][n][k] bf16, 64x64 tiles, vectorized both sides.
__global__ __launch_bounds__(256) void k_transpose_cast(const float* __restrict__ W,
                                                        bf16* __restrict__ Wt) {
  __shared__ float tile[64][65];
  const size_t mat = (size_t)HID * HID;
  const float* Wz = W + mat * blockIdx.z;
  bf16* Wtz = Wt + mat * blockIdx.z;
  int bn = blockIdx.x * 64;   // n base
  int bk = blockIdx.y * 64;   // k base
  int t = threadIdx.x;
  {
    int r = t >> 4, c = (t & 15) * 4;
    #pragma unroll
    for (int i = 0; i < 4; i++) {
      float4 v = *(const float4*)(Wz + (size_t)(bk + r + 16 * i) * HID + bn + c);
      tile[r + 16 * i][c] = v.x; tile[r + 16 * i][c + 1] = v.y;
      tile[r + 16 * i][c + 2] = v.z; tile[r + 16 * i][c + 3] = v.w;
    }
  }
  __syncthreads();
  {
    int n = t >> 2, kc = (t & 3) * 16;
    bf16x8 o0, o1;
    #pragma unroll
    for (int j = 0; j < 8; j++) o0[j] = (bf16)tile[kc + j][n];
    #pragma unroll
    for (int j = 0; j < 8; j++) o1[j] = (bf16)tile[kc + 8 + j][n];
    bf16* dst = Wtz + (size_t)(bn + n) * HID + bk + kc;
    *(bf16x8*)dst = o0;
    *(bf16x8*)(dst + 8) = o1;
  }
}

// y = rmsnorm(relu(x)) * nw -> bf16 Y;  also write relu(x) -> bf16 R (residual).
__global__ __launch_bounds__(256) void k_pre(const float* __restrict__ x,
                                             const float* __restrict__ nw,
                                             bf16* __restrict__ Y,
                                             bf16* __restrict__ R) {
  size_t base = (size_t)blockIdx.x * HID + threadIdx.x * 8;
  float4 v0 = *(const float4*)(x + base);
  float4 v1 = *(const float4*)(x + base + 4);
  float z[8] = {v0.x, v0.y, v0.z, v0.w, v1.x, v1.y, v1.z, v1.w};
  float ss = 0.f;
  #pragma unroll
  for (int i = 0; i < 8; i++) { z[i] = fmaxf(z[i], 0.f); ss += z[i] * z[i]; }
  float tot = block_sum256(ss);
  float s = rsqrtf(tot * (1.0f / HID) + EPSF);
  bf16x8 rr;
  #pragma unroll
  for (int i = 0; i < 8; i++) rr[i] = (bf16)z[i];
  *(bf16x8*)(R + base) = rr;
  int j0 = threadIdx.x * 8;
  float4 w0 = *(const float4*)(nw + j0);
  float4 w1 = *(const float4*)(nw + j0 + 4);
  float wv[8] = {w0.x, w0.y, w0.z, w0.w, w1.x, w1.y, w1.z, w1.w};
  bf16x8 o;
  #pragma unroll
  for (int i = 0; i < 8; i++) o[i] = (bf16)(z[i] * s * wv[i]);
  *(bf16x8*)(Y + base) = o;
}

// resid = residIn + Cin ; y = rmsnorm(resid)*nw ; per-128-group ue8m0 quant
__global__ __launch_bounds__(256) void k_fuse_quant(const bf16* __restrict__ residIn,
                                                    const bf16* __restrict__ Cin,
                                                    const float* __restrict__ nw,
                                                    bf16* __restrict__ residOut,
                                                    bf16* __restrict__ Aout,
                                                    float* __restrict__ scaleOut) {
  int row = blockIdx.x;
  int j0 = threadIdx.x * 8;
  size_t base = (size_t)row * HID + j0;
  bf16x8 c  = *(const bf16x8*)(Cin + base);
  bf16x8 rv = *(const bf16x8*)(residIn + base);
  float r[8]; float ss = 0.f;
  #pragma unroll
  for (int i = 0; i < 8; i++) { r[i] = (float)rv[i] + (float)c[i]; ss += r[i] * r[i]; }
  float tot = block_sum256(ss);
  float s = rsqrtf(tot * (1.0f / HID) + EPSF);

  bf16x8 ro;
  #pragma unroll
  for (int i = 0; i < 8; i++) ro[i] = (bf16)r[i];
  *(bf16x8*)(residOut + base) = ro;

  float4 w0 = *(const float4*)(nw + j0);
  float4 w1 = *(const float4*)(nw + j0 + 4);
  float wv[8] = {w0.x, w0.y, w0.z, w0.w, w1.x, w1.y, w1.z, w1.w};
  float y[8], amax = 0.f;
  #pragma unroll
  for (int i = 0; i < 8; i++) { y[i] = r[i] * s * wv[i]; amax = fmaxf(amax, fabsf(y[i])); }
  amax = fmaxf(amax, __shfl_xor(amax, 1, 64));
  amax = fmaxf(amax, __shfl_xor(amax, 2, 64));
  amax = fmaxf(amax, __shfl_xor(amax, 4, 64));
  amax = fmaxf(amax, __shfl_xor(amax, 8, 64));
  float scale = ue8m0_scale(amax);
  float inv = 1.0f / scale;          // exact: scale is a power of 2
  bf16x8 q;
  #pragma unroll
  for (int i = 0; i < 8; i++) {
    float t = fminf(fmaxf(y[i] * inv, -448.f), 448.f);
    q[i] = (bf16)fp8_e4m3_rne(t);    // fp8 values are exact in bf16
  }
  *(bf16x8*)(Aout + base) = q;
  if ((threadIdx.x & 15) == 0) scaleOut[(size_t)row * NGRP + (j0 >> 7)] = scale;
}

// y4 = rmsnorm(residIn + Cin) * nw -> f32 out.
__global__ __launch_bounds__(256) void k_final(const bf16* __restrict__ residIn,
                                               const bf16* __restrict__ Cin,
                                               const float* __restrict__ nw,
                                               float* __restrict__ out) {
  size_t base = (size_t)blockIdx.x * HID + threadIdx.x * 8;
  bf16x8 c  = *(const bf16x8*)(Cin + base);
  bf16x8 rv = *(const bf16x8*)(residIn + base);
  float r[8]; float ss = 0.f;
  #pragma unroll
  for (int i = 0; i < 8; i++) { r[i] = (float)rv[i] + (float)c[i]; ss += r[i] * r[i]; }
  float tot = block_sum256(ss);
  float s = rsqrtf(tot * (1.0f / HID) + EPSF);
  int j0 = threadIdx.x * 8;
  float4 w0 = *(const float4*)(nw + j0);
  float4 w1 = *(const float4*)(nw + j0 + 4);
  float wv[8] = {w0.x, w0.y, w0.z, w0.w, w1.x, w1.y, w1.z, w1.w};
  float4 o0, o1;
  o0.x = r[0]*s*wv[0]; o0.y = r[1]*s*wv[1]; o0.z = r[2]*s*wv[2]; o0.w = r[3]*s*wv[3];
  o1.x = r[4]*s*wv[4]; o1.y = r[5]*s*wv[5]; o1.z = r[6]*s*wv[6]; o1.w = r[7]*s*wv[7];
  *(float4*)(out + base) = o0;
  *(float4*)(out + base + 4) = o1;
}

// C[M][N] = A[M][K] * B^T[N][K], bf16 in, fp32 acc, bf16 out.
// 8-phase schedule (round 4) with round-5 changes:
//  (1) ONE barrier per phase (4/tile, was 8). Safety audit: every ds_read is
//      issued BEFORE its phase's barrier; every DMA stage that overwrites a
//      region is issued AFTER a barrier that follows that region's reads:
//        ph0 stage A0(t+1)->other: prev contents read at t-1:ph0 (4 bars ago)
//        ph1 stage A1(t+1)->other: read at t-1:ph2 (3 bars ago)
//        ph2 stage B0(t+2)->cur:   read at t:ph0  (2 bars ago)
//        ph3 stage B1(t+2)->cur:   read at t:ph1  (1 bar ago)
//      MFMA is register-only; lagging waves can't touch LDS. vmcnt(4)+bar at
//      ph3 guarantees all waves' t+1 stages landed before t+1:ph0 reads.
//  (2) LDS-transposed epilogue: acc -> LDS bf16 [256][256] (LDS dead after
//      K-loop, exactly 128 KiB), then fully-coalesced bf16x8 stores
//      (16 B/lane, wave covers 2 contiguous 512-B rows). Replaces 128 scalar
//      2-B global stores per thread.
// vmcnt(4) once per K-tile (never 0 in-loop). Swizzle: chunk pc = lc^(row&7),
// pre-swizzled global source (DMA writes linearly), same XOR on ds_read ->
// conflict-free (measured 0). Grid map: x=b&7, j=b>>3, bm=8x+(j&7), bn=j>>3
// -> per-XCD L2-resident B panels (FETCH 98 MB).
__global__ __launch_bounds__(512, 2) void k_gemm(const bf16* __restrict__ A,
                                                 const bf16* __restrict__ B,
                                                 bf16* __restrict__ C,
                                                 int M, int N, int K) {
  // buffer layout (64 KiB each, 2 buffers):
  //   A: [0,32768)  rows 0..255 * 128 B   (h0 = rows 0-127, h1 = 128-255)
  //   B: [32768,65536) same
  __shared__ __align__(16) char lds[2 * 65536];
  int b = blockIdx.x;
  int x = b & 7, j = b >> 3;
  int bm = x * 8 + (j & 7);
  int bn = j >> 3;
  int tid = threadIdx.x;
  int wave = tid >> 6, lane = tid & 63;
  int q = lane >> 4, rr = lane & 15;
  int wm = wave >> 2, wn = wave & 3;      // 2 x 4 wave grid, per-wave 128x64

  // staging source pointers (pre-swizzled). Per half-tile (128 rows x 64 bf16
  // = 16 KiB = 1024 chunks of 16 B), thread covers chunks m = ic*512 + tid:
  //   local row lr = m>>3, physical chunk cl = m&7, logical src chunk
  //   lc = cl ^ (lr&7). Dest (linear) = region + m*16.
  const bf16* aS[2][2]; const bf16* bS[2][2];   // [half][ic]
  #pragma unroll
  for (int ic = 0; ic < 2; ic++) {
    int m = ic * 512 + tid;
    int lr = m >> 3, cl = m & 7, lc = cl ^ (lr & 7);
    #pragma unroll
    for (int h = 0; h < 2; h++) {
      aS[h][ic] = A + (size_t)(bm * 256 + h * 128 + lr) * K + lc * 8;
      bS[h][ic] = B + (size_t)(bn * 256 + h * 128 + lr) * K + lc * 8;
    }
  }

  const int NT = K / 64;                  // 32 K-tiles
  const int pc0 = (q ^ (rr & 7)) << 4;    // swizzled chunk byte-offset, k-slot 0

#define STAGE_A(h, tt) {                                                       \
    int ts_ = (tt) < NT ? (tt) : (NT - 1);                                     \
    char* d_ = lds + (((tt) & 1) * 65536) + (h) * 16384 + tid * 16;            \
    async_load16(aS[h][0] + (size_t)ts_ * 64, d_);                             \
    async_load16(aS[h][1] + (size_t)ts_ * 64, d_ + 8192); }
#define STAGE_B(h, tt) {                                                       \
    int ts_ = (tt) < NT ? (tt) : (NT - 1);                                     \
    char* d_ = lds + (((tt) & 1) * 65536) + 32768 + (h) * 16384 + tid * 16;    \
    async_load16(bS[h][0] + (size_t)ts_ * 64, d_);                             \
    async_load16(bS[h][1] + (size_t)ts_ * 64, d_ + 8192); }

  f32x4 acc[8][4];
  #pragma unroll
  for (int mf = 0; mf < 8; mf++)
    #pragma unroll
    for (int nf = 0; nf < 4; nf++)
      #pragma unroll
      for (int e = 0; e < 4; e++) acc[mf][nf][e] = 0.f;

  // prologue: tile0 {A0,A1,B0,B1}, tile1 {B0,B1}; vmcnt(4) leaves tile1's B
  // (4 vmem instrs) in flight, guarantees tile0 landed. Loop stages the rest.
  STAGE_A(0, 0) STAGE_A(1, 0) STAGE_B(0, 0) STAGE_B(1, 0)
  STAGE_B(0, 1) STAGE_B(1, 1)
  asm volatile("s_waitcnt vmcnt(4)" ::: "memory");
  asm volatile("s_barrier" ::: "memory");

#define MFMA8(AF, BF, MO, NO)                                                  \
    __builtin_amdgcn_s_setprio(1);                                             \
    _Pragma("unroll")                                                          \
    for (int s = 0; s < 2; s++)                                                \
      _Pragma("unroll")                                                        \
      for (int f = 0; f < 4; f++)                                              \
        _Pragma("unroll")                                                      \
        for (int n2 = 0; n2 < 2; n2++)                                         \
          acc[(MO) + f][(NO) + n2] = __builtin_amdgcn_mfma_f32_16x16x32_bf16(  \
              AF[f][s], BF[n2][s], acc[(MO) + f][(NO) + n2], 0, 0, 0);         \
    __builtin_amdgcn_s_setprio(0);

#define TILE(tau, XB) {                                                        \
    const char* Ax_ = lds + (XB) + wm * 16384;                                 \
    const char* Bx_ = lds + (XB) + 32768 + wn * 8192;                          \
    bf16x8 a0_[4][2], a1_[4][2], b0_[2][2], b1_[2][2];                         \
    /* ---- ph0: read A-h0(8)+B-j0(4); stage A0(t+1); bar; MFMA Q00 ---- */    \
    _Pragma("unroll")                                                          \
    for (int f = 0; f < 4; f++)                                                \
      _Pragma("unroll")                                                        \
      for (int s = 0; s < 2; s++)                                              \
        a0_[f][s] = *(const bf16x8*)(Ax_ + f * 2048 + rr * 128 +               \
                                     (pc0 ^ (s << 6)));                        \
    _Pragma("unroll")                                                          \
    for (int n2 = 0; n2 < 2; n2++)                                             \
      _Pragma("unroll")                                                        \
      for (int s = 0; s < 2; s++)                                              \
        b0_[n2][s] = *(const bf16x8*)(Bx_ + n2 * 2048 + rr * 128 +             \
                                      (pc0 ^ (s << 6)));                       \
    STAGE_A(0, (tau) + 1)                                                      \
    asm volatile("s_barrier" ::: "memory");                                    \
    MFMA8(a0_, b0_, 0, 0)                                                      \
    /* ---- ph1: read B-j1(4); stage A1(t+1); bar; MFMA Q01 ---- */            \
    _Pragma("unroll")                                                          \
    for (int n2 = 0; n2 < 2; n2++)                                             \
      _Pragma("unroll")                                                        \
      for (int s = 0; s < 2; s++)                                              \
        b1_[n2][s] = *(const bf16x8*)(Bx_ + 4096 + n2 * 2048 + rr * 128 +      \
                                      (pc0 ^ (s << 6)));                       \
    STAGE_A(1, (tau) + 1)                                                      \
    asm volatile("s_barrier" ::: "memory");                                    \
    MFMA8(a0_, b1_, 0, 2)                                                      \
    /* ---- ph2: read A-h1(8); stage B0(t+2); bar; MFMA Q10 ---- */            \
    _Pragma("unroll")                                                          \
    for (int f = 0; f < 4; f++)                                                \
      _Pragma("unroll")                                                        \
      for (int s = 0; s < 2; s++)                                              \
        a1_[f][s] = *(const bf16x8*)(Ax_ + 8192 + f * 2048 + rr * 128 +        \
                                     (pc0 ^ (s << 6)));                        \
    STAGE_B(0, (tau) + 2)                                                      \
    asm volatile("s_barrier" ::: "memory");                                    \
    MFMA8(a1_, b0_, 4, 0)                                                      \
    /* ---- ph3: stage B1(t+2); vmcnt(4) (tile t+1 landed); bar; MFMA Q11 */   \
    STAGE_B(1, (tau) + 2)                                                      \
    asm volatile("s_waitcnt vmcnt(4)" ::: "memory");                           \
    asm volatile("s_barrier" ::: "memory");                                    \
    MFMA8(a1_, b1_, 4, 2)                                                      \
  }

  for (int tt = 0; tt < NT; tt += 2) {
    TILE(tt, 0)
    TILE(tt + 1, 65536)
  }
#undef TILE
#undef MFMA8
#undef STAGE_A
#undef STAGE_B

  // ---- epilogue: drain DMA, reuse LDS as a [256][256] bf16 C-tile ----
  asm volatile("s_waitcnt vmcnt(0)" ::: "memory");
  __syncthreads();
  {
    char* cb = lds;
    #pragma unroll
    for (int mf = 0; mf < 8; mf++)
      #pragma unroll
      for (int nf = 0; nf < 4; nf++)
        #pragma unroll
        for (int tt = 0; tt < 4; tt++) {
          int row = wm * 128 + mf * 16 + q * 4 + tt;
          int col = wn * 64 + nf * 16 + rr;
          *(bf16*)(cb + row * 512 + col * 2) = (bf16)acc[mf][nf][tt];
        }
  }
  __syncthreads();
  {
    const char* cb = lds;
    #pragma unroll
    for (int i = 0; i < 16; i++) {
      int chunk = i * 512 + tid;          // 8192 chunks of 16 B
      int row = chunk >> 5, cc = chunk & 31;
      bf16x8 v = *(const bf16x8*)(cb + chunk * 16);
      *(bf16x8*)(C + (size_t)(bm * 256 + row) * N + bn * 256 + cc * 8) = v;
    }
  }
}

// ---------------- launch ----------------

extern "C" void kernel_launch(void* const* d_in, const int* in_sizes, int n_in,
                              void* d_out, int out_size, void* d_ws, size_t ws_size,
                              hipStream_t stream) {
  const float* x      = (const float*)d_in[0];
  const float* norm_w = (const float*)d_in[1];
  const float* w      = (const float*)d_in[2];

  float* out   = (float*)d_out;
  float* y4o   = out;
  float* s2o   = out + (size_t)NTOK * HID;           // y2_s [16384,16]
  float* s3o   = s2o + (size_t)NTOK * NGRP;          // y3_s [16384,16]

  char* ws = (char*)d_ws;
  const size_t WT_B = (size_t)3 * HID * HID * 2;     // 25,165,824
  const size_t AB_B = (size_t)NTOK * HID * 2;        // 67,108,864
  bf16* Wt   = (bf16*)ws;
  bf16* Abuf = (bf16*)(ws + WT_B);
  bf16* Cbuf = (bf16*)(ws + WT_B + AB_B);
  bf16* Rbuf = (bf16*)(ws + WT_B + 2 * AB_B);
  const size_t MATE = (size_t)HID * HID;

  dim3 gT(HID / 64, HID / 64, 3);
  int  gG = (NTOK / 256) * (HID / 256);    // 512 blocks; in-kernel XCD mapping

  k_transpose_cast<<<gT, 256, 0, stream>>>(w, Wt);
  k_pre<<<NTOK, 256, 0, stream>>>(x, norm_w, Abuf, Rbuf);
  k_gemm<<<gG, 512, 0, stream>>>(Abuf, Wt, Cbuf, NTOK, HID, HID);
  k_fuse_quant<<<NTOK, 256, 0, stream>>>(Rbuf, Cbuf, norm_w + HID, Rbuf, Abuf, s2o);
  k_gemm<<<gG, 512, 0, stream>>>(Abuf, Wt + MATE, Cbuf, NTOK, HID, HID);
  k_fuse_quant<<<NTOK, 256, 0, stream>>>(Rbuf, Cbuf, norm_w + 2 * HID, Rbuf, Abuf, s3o);
  k_gemm<<<gG, 512, 0, stream>>>(Abuf, Wt + 2 * MATE, Cbuf, NTOK, HID, HID);
  k_final<<<NTOK, 256, 0, stream>>>(Rbuf, Cbuf, norm_w + 3 * HID, y4o);
}

// Round 6
// 698.558 us; speedup vs baseline: 1.1451x; 1.0052x over previous
//
#include <hip/hip_runtime.h>
#include <stdint.h>
#include <math.h>

#define NTOK 16384
#define HID  2048
#define NGRP 16          // HID/128
#define EPSF 1e-5f

typedef __bf16 bf16;
typedef __bf16 bf16x8 __attribute__((ext_vector_type(8)));
typedef float  f32x4  __attribute__((ext_vector_type(4)));

// ---------------- helpers ----------------

__device__ __forceinline__ void async_load16(const void* g, void* l) {
  __builtin_amdgcn_global_load_lds((const __attribute__((address_space(1))) void*)g,
                                   (__attribute__((address_space(3))) void*)l, 16, 0, 0);
}

// bit-exact fp8 e4m3fn round-to-nearest-even; input must be pre-clipped to [-448,448]
__device__ __forceinline__ float fp8_e4m3_rne(float v) {
  float a = fabsf(v);
  float s = (v < 0.f) ? -1.f : 1.f;
  if (a < 0.015625f) {                 // below 2^-6: fp8 subnormal, quantum 2^-9
    float r = rintf(a * 512.0f);       // v_rndne = RNE
    return s * r * 0.001953125f;
  }
  uint32_t u = __float_as_uint(a);
  u = (u + 0x7FFFFu + ((u >> 20) & 1u)) & 0xFFF00000u;  // RNE to 3 mantissa bits
  return s * __uint_as_float(u);
}

__device__ __forceinline__ float block_sum256(float v) {
  __shared__ float sh[4];
  #pragma unroll
  for (int o = 32; o > 0; o >>= 1) v += __shfl_xor(v, o, 64);
  if ((threadIdx.x & 63) == 0) sh[threadIdx.x >> 6] = v;
  __syncthreads();
  return sh[0] + sh[1] + sh[2] + sh[3];
}

// ue8m0 scale: exp2(ceil(log2(max(amax,1e-10)/448))), emulating numpy fp32 semantics
__device__ __forceinline__ float ue8m0_scale(float amax) {
  float v = fmaxf(amax, 1e-10f) / 448.0f;
  float l = (float)log2((double)v);    // correctly-rounded; exact at powers of 2
  return exp2f(ceilf(l));
}

// ---------------- kernels ----------------

// w[z][k][n] f32 -> Wt[z][n][k] bf16, 64x64 tiles, vectorized both sides.
__global__ __launch_bounds__(256) void k_transpose_cast(const float* __restrict__ W,
                                                        bf16* __restrict__ Wt) {
  __shared__ float tile[64][65];
  const size_t mat = (size_t)HID * HID;
  const float* Wz = W + mat * blockIdx.z;
  bf16* Wtz = Wt + mat * blockIdx.z;
  int bn = blockIdx.x * 64;   // n base
  int bk = blockIdx.y * 64;   // k base
  int t = threadIdx.x;
  {
    int r = t >> 4, c = (t & 15) * 4;
    #pragma unroll
    for (int i = 0; i < 4; i++) {
      float4 v = *(const float4*)(Wz + (size_t)(bk + r + 16 * i) * HID + bn + c);
      tile[r + 16 * i][c] = v.x; tile[r + 16 * i][c + 1] = v.y;
      tile[r + 16 * i][c + 2] = v.z; tile[r + 16 * i][c + 3] = v.w;
    }
  }
  __syncthreads();
  {
    int n = t >> 2, kc = (t & 3) * 16;
    bf16x8 o0, o1;
    #pragma unroll
    for (int j = 0; j < 8; j++) o0[j] = (bf16)tile[kc + j][n];
    #pragma unroll
    for (int j = 0; j < 8; j++) o1[j] = (bf16)tile[kc + 8 + j][n];
    bf16* dst = Wtz + (size_t)(bn + n) * HID + bk + kc;
    *(bf16x8*)dst = o0;
    *(bf16x8*)(dst + 8) = o1;
  }
}

// y = rmsnorm(relu(x)) * nw -> bf16 Y;  also write relu(x) -> bf16 R (residual).
__global__ __launch_bounds__(256) void k_pre(const float* __restrict__ x,
                                             const float* __restrict__ nw,
                                             bf16* __restrict__ Y,
                                             bf16* __restrict__ R) {
  size_t base = (size_t)blockIdx.x * HID + threadIdx.x * 8;
  float4 v0 = *(const float4*)(x + base);
  float4 v1 = *(const float4*)(x + base + 4);
  float z[8] = {v0.x, v0.y, v0.z, v0.w, v1.x, v1.y, v1.z, v1.w};
  float ss = 0.f;
  #pragma unroll
  for (int i = 0; i < 8; i++) { z[i] = fmaxf(z[i], 0.f); ss += z[i] * z[i]; }
  float tot = block_sum256(ss);
  float s = rsqrtf(tot * (1.0f / HID) + EPSF);
  bf16x8 rr;
  #pragma unroll
  for (int i = 0; i < 8; i++) rr[i] = (bf16)z[i];
  *(bf16x8*)(R + base) = rr;
  int j0 = threadIdx.x * 8;
  float4 w0 = *(const float4*)(nw + j0);
  float4 w1 = *(const float4*)(nw + j0 + 4);
  float wv[8] = {w0.x, w0.y, w0.z, w0.w, w1.x, w1.y, w1.z, w1.w};
  bf16x8 o;
  #pragma unroll
  for (int i = 0; i < 8; i++) o[i] = (bf16)(z[i] * s * wv[i]);
  *(bf16x8*)(Y + base) = o;
}

// resid = residIn + Cin ; y = rmsnorm(resid)*nw ; per-128-group ue8m0 quant
__global__ __launch_bounds__(256) void k_fuse_quant(const bf16* __restrict__ residIn,
                                                    const bf16* __restrict__ Cin,
                                                    const float* __restrict__ nw,
                                                    bf16* __restrict__ residOut,
                                                    bf16* __restrict__ Aout,
                                                    float* __restrict__ scaleOut) {
  int row = blockIdx.x;
  int j0 = threadIdx.x * 8;
  size_t base = (size_t)row * HID + j0;
  bf16x8 c  = *(const bf16x8*)(Cin + base);
  bf16x8 rv = *(const bf16x8*)(residIn + base);
  float r[8]; float ss = 0.f;
  #pragma unroll
  for (int i = 0; i < 8; i++) { r[i] = (float)rv[i] + (float)c[i]; ss += r[i] * r[i]; }
  float tot = block_sum256(ss);
  float s = rsqrtf(tot * (1.0f / HID) + EPSF);

  bf16x8 ro;
  #pragma unroll
  for (int i = 0; i < 8; i++) ro[i] = (bf16)r[i];
  *(bf16x8*)(residOut + base) = ro;

  float4 w0 = *(const float4*)(nw + j0);
  float4 w1 = *(const float4*)(nw + j0 + 4);
  float wv[8] = {w0.x, w0.y, w0.z, w0.w, w1.x, w1.y, w1.z, w1.w};
  float y[8], amax = 0.f;
  #pragma unroll
  for (int i = 0; i < 8; i++) { y[i] = r[i] * s * wv[i]; amax = fmaxf(amax, fabsf(y[i])); }
  amax = fmaxf(amax, __shfl_xor(amax, 1, 64));
  amax = fmaxf(amax, __shfl_xor(amax, 2, 64));
  amax = fmaxf(amax, __shfl_xor(amax, 4, 64));
  amax = fmaxf(amax, __shfl_xor(amax, 8, 64));
  float scale = ue8m0_scale(amax);
  float inv = 1.0f / scale;          // exact: scale is a power of 2
  bf16x8 q;
  #pragma unroll
  for (int i = 0; i < 8; i++) {
    float t = fminf(fmaxf(y[i] * inv, -448.f), 448.f);
    q[i] = (bf16)fp8_e4m3_rne(t);    // fp8 values are exact in bf16
  }
  *(bf16x8*)(Aout + base) = q;
  if ((threadIdx.x & 15) == 0) scaleOut[(size_t)row * NGRP + (j0 >> 7)] = scale;
}

// y4 = rmsnorm(residIn + Cin) * nw -> f32 out.
__global__ __launch_bounds__(256) void k_final(const bf16* __restrict__ residIn,
                                               const bf16* __restrict__ Cin,
                                               const float* __restrict__ nw,
                                               float* __restrict__ out) {
  size_t base = (size_t)blockIdx.x * HID + threadIdx.x * 8;
  bf16x8 c  = *(const bf16x8*)(Cin + base);
  bf16x8 rv = *(const bf16x8*)(residIn + base);
  float r[8]; float ss = 0.f;
  #pragma unroll
  for (int i = 0; i < 8; i++) { r[i] = (float)rv[i] + (float)c[i]; ss += r[i] * r[i]; }
  float tot = block_sum256(ss);
  float s = rsqrtf(tot * (1.0f / HID) + EPSF);
  int j0 = threadIdx.x * 8;
  float4 w0 = *(const float4*)(nw + j0);
  float4 w1 = *(const float4*)(nw + j0 + 4);
  float wv[8] = {w0.x, w0.y, w0.z, w0.w, w1.x, w1.y, w1.z, w1.w};
  float4 o0, o1;
  o0.x = r[0]*s*wv[0]; o0.y = r[1]*s*wv[1]; o0.z = r[2]*s*wv[2]; o0.w = r[3]*s*wv[3];
  o1.x = r[4]*s*wv[4]; o1.y = r[5]*s*wv[5]; o1.z = r[6]*s*wv[6]; o1.w = r[7]*s*wv[7];
  *(float4*)(out + base) = o0;
  *(float4*)(out + base + 4) = o1;
}

// C[M][N] = A[M][K] * B^T[N][K], bf16 in, fp32 acc, bf16 out.
// 8-phase schedule; round-6 changes:
//  (1) FRAGMENT READS ROTATED ONE PHASE AHEAD. Each phase's MFMA consumes
//      frags read in the PREVIOUS phase (full MFMA cluster + barrier between
//      issue and use -> compiler emits counted lgkmcnt, LDS drain overlaps
//      MFMA). Read placement: prev-ph3 -> {A-h0,B-j0}(next tile, 12 reads),
//      ph0 -> B-j1(4), ph1 -> A-h1(8), ph2 -> none.
//      Hazard ledger unchanged: vmcnt(4)+bar at ph3 drains exactly tile t+1's
//      A+B (leaves B(t+2)x4 in flight), so the ph3 next-buffer reads are safe;
//      every stage still lands >=1 barrier after its region's last read drain:
//        ph0 stage A0(t+1)->other: region read drained t-1:ph0  (4 bars)
//        ph1 stage A1(t+1)->other: drained t-1:ph2              (3 bars)
//        ph2 stage B0(t+2)->cur:   drained t:ph0                (2 bars)
//        ph3 stage B1(t+2)->cur:   drained t:ph1                (1 bar)
//  (2) Epilogue LDS C-tile XOR-swizzle: col ^= ((row>>2)&3)<<4 on the scatter
//      write (kills the 8-way q-group conflict, SQ_LDS_BANK_CONFLICT 1.05M),
//      inverse chunk ^= e<<1 on the coalesced read-back (permutation within
//      row -> still 2 lanes/bank, free).
// vmcnt(4) once per K-tile (never 0 in-loop). Staging swizzle: chunk
// pc = lc^(row&7), pre-swizzled global source, same XOR on ds_read. Grid map:
// x=b&7, j=b>>3, bm=8x+(j&7), bn=j>>3 -> per-XCD L2-resident B (FETCH 98 MB).
__global__ __launch_bounds__(512, 2) void k_gemm(const bf16* __restrict__ A,
                                                 const bf16* __restrict__ B,
                                                 bf16* __restrict__ C,
                                                 int M, int N, int K) {
  // buffer layout (64 KiB each, 2 buffers):
  //   A: [0,32768)  rows 0..255 * 128 B   (h0 = rows 0-127, h1 = 128-255)
  //   B: [32768,65536) same
  __shared__ __align__(16) char lds[2 * 65536];
  int b = blockIdx.x;
  int x = b & 7, j = b >> 3;
  int bm = x * 8 + (j & 7);
  int bn = j >> 3;
  int tid = threadIdx.x;
  int wave = tid >> 6, lane = tid & 63;
  int q = lane >> 4, rr = lane & 15;
  int wm = wave >> 2, wn = wave & 3;      // 2 x 4 wave grid, per-wave 128x64

  // staging source pointers (pre-swizzled). Per half-tile (128 rows x 64 bf16
  // = 16 KiB = 1024 chunks of 16 B), thread covers chunks m = ic*512 + tid:
  //   local row lr = m>>3, physical chunk cl = m&7, logical src chunk
  //   lc = cl ^ (lr&7). Dest (linear) = region + m*16.
  const bf16* aS[2][2]; const bf16* bS[2][2];   // [half][ic]
  #pragma unroll
  for (int ic = 0; ic < 2; ic++) {
    int m = ic * 512 + tid;
    int lr = m >> 3, cl = m & 7, lc = cl ^ (lr & 7);
    #pragma unroll
    for (int h = 0; h < 2; h++) {
      aS[h][ic] = A + (size_t)(bm * 256 + h * 128 + lr) * K + lc * 8;
      bS[h][ic] = B + (size_t)(bn * 256 + h * 128 + lr) * K + lc * 8;
    }
  }

  const int NT = K / 64;                  // 32 K-tiles
  const int pc0 = (q ^ (rr & 7)) << 4;    // swizzled chunk byte-offset, k-slot 0

#define STAGE_A(h, tt) {                                                       \
    int ts_ = (tt) < NT ? (tt) : (NT - 1);                                     \
    char* d_ = lds + (((tt) & 1) * 65536) + (h) * 16384 + tid * 16;            \
    async_load16(aS[h][0] + (size_t)ts_ * 64, d_);                             \
    async_load16(aS[h][1] + (size_t)ts_ * 64, d_ + 8192); }
#define STAGE_B(h, tt) {                                                       \
    int ts_ = (tt) < NT ? (tt) : (NT - 1);                                     \
    char* d_ = lds + (((tt) & 1) * 65536) + 32768 + (h) * 16384 + tid * 16;    \
    async_load16(bS[h][0] + (size_t)ts_ * 64, d_);                             \
    async_load16(bS[h][1] + (size_t)ts_ * 64, d_ + 8192); }

  f32x4 acc[8][4];
  #pragma unroll
  for (int mf = 0; mf < 8; mf++)
    #pragma unroll
    for (int nf = 0; nf < 4; nf++)
      #pragma unroll
      for (int e = 0; e < 4; e++) acc[mf][nf][e] = 0.f;

  // prologue: tile0 {A0,A1,B0,B1}, tile1 {B0,B1}; vmcnt(4) drains tile0
  // (leaves tile1's B x4 in flight = loop invariant), barrier, then the
  // initial Q00 frag reads (tile0 A-h0 + B-j0).
  STAGE_A(0, 0) STAGE_A(1, 0) STAGE_B(0, 0) STAGE_B(1, 0)
  STAGE_B(0, 1) STAGE_B(1, 1)
  asm volatile("s_waitcnt vmcnt(4)" ::: "memory");
  asm volatile("s_barrier" ::: "memory");

  bf16x8 aF[4][2], bF[2][2], aG[4][2], bG[2][2];
  {
    const char* Ax = lds + wm * 16384;
    const char* Bx = lds + 32768 + wn * 8192;
    #pragma unroll
    for (int f = 0; f < 4; f++)
      #pragma unroll
      for (int s = 0; s < 2; s++)
        aF[f][s] = *(const bf16x8*)(Ax + f * 2048 + rr * 128 + (pc0 ^ (s << 6)));
    #pragma unroll
    for (int n2 = 0; n2 < 2; n2++)
      #pragma unroll
      for (int s = 0; s < 2; s++)
        bF[n2][s] = *(const bf16x8*)(Bx + n2 * 2048 + rr * 128 + (pc0 ^ (s << 6)));
  }

#define MFMA8(AF, BF, MO, NO)                                                  \
    __builtin_amdgcn_s_setprio(1);                                             \
    _Pragma("unroll")                                                          \
    for (int s = 0; s < 2; s++)                                                \
      _Pragma("unroll")                                                        \
      for (int f = 0; f < 4; f++)                                              \
        _Pragma("unroll")                                                      \
        for (int n2 = 0; n2 < 2; n2++)                                         \
          acc[(MO) + f][(NO) + n2] = __builtin_amdgcn_mfma_f32_16x16x32_bf16(  \
              AF[f][s], BF[n2][s], acc[(MO) + f][(NO) + n2], 0, 0, 0);         \
    __builtin_amdgcn_s_setprio(0);

#define TILE(tau, XB, AC, BC, AN, BN) {                                        \
    const char* Ax_  = lds + (XB) + wm * 16384;                                \
    const char* Bx_  = lds + (XB) + 32768 + wn * 8192;                         \
    const char* AxN_ = lds + ((XB) ^ 65536) + wm * 16384;                      \
    const char* BxN_ = lds + ((XB) ^ 65536) + 32768 + wn * 8192;               \
    bf16x8 a1_[4][2], b1_[2][2];                                               \
    /* ph0: stage A0(t+1); bar; issue B-j1 reads; MFMA Q00 (prev-ph3 frags) */ \
    STAGE_A(0, (tau) + 1)                                                      \
    asm volatile("s_barrier" ::: "memory");                                    \
    _Pragma("unroll")                                                          \
    for (int n2 = 0; n2 < 2; n2++)                                             \
      _Pragma("unroll")                                                        \
      for (int s = 0; s < 2; s++)                                              \
        b1_[n2][s] = *(const bf16x8*)(Bx_ + 4096 + n2 * 2048 + rr * 128 +      \
                                      (pc0 ^ (s << 6)));                       \
    MFMA8(AC, BC, 0, 0)                                                        \
    /* ph1: stage A1(t+1); bar; issue A-h1 reads; MFMA Q01 (b1_ from ph0) */   \
    STAGE_A(1, (tau) + 1)                                                      \
    asm volatile("s_barrier" ::: "memory");                                    \
    _Pragma("unroll")                                                          \
    for (int f = 0; f < 4; f++)                                                \
      _Pragma("unroll")                                                        \
      for (int s = 0; s < 2; s++)                                              \
        a1_[f][s] = *(const bf16x8*)(Ax_ + 8192 + f * 2048 + rr * 128 +        \
                                     (pc0 ^ (s << 6)));                        \
    MFMA8(AC, b1_, 0, 2)                                                       \
    /* ph2: stage B0(t+2); bar; MFMA Q10 (a1_ from ph1) */                     \
    STAGE_B(0, (tau) + 2)                                                      \
    asm volatile("s_barrier" ::: "memory");                                    \
    MFMA8(a1_, BC, 4, 0)                                                       \
    /* ph3: stage B1(t+2); vmcnt(4) [tile t+1 landed]; bar;                    \
       issue next tile's A-h0+B-j0 reads; MFMA Q11 */                          \
    STAGE_B(1, (tau) + 2)                                                      \
    asm volatile("s_waitcnt vmcnt(4)" ::: "memory");                           \
    asm volatile("s_barrier" ::: "memory");                                    \
    _Pragma("unroll")                                                          \
    for (int f = 0; f < 4; f++)                                                \
      _Pragma("unroll")                                                        \
      for (int s = 0; s < 2; s++)                                              \
        AN[f][s] = *(const bf16x8*)(AxN_ + f * 2048 + rr * 128 +               \
                                    (pc0 ^ (s << 6)));                         \
    _Pragma("unroll")                                                          \
    for (int n2 = 0; n2 < 2; n2++)                                             \
      _Pragma("unroll")                                                        \
      for (int s = 0; s < 2; s++)                                              \
        BN[n2][s] = *(const bf16x8*)(BxN_ + n2 * 2048 + rr * 128 +             \
                                     (pc0 ^ (s << 6)));                        \
    MFMA8(a1_, b1_, 4, 2)                                                      \
  }

  for (int tt = 0; tt < NT; tt += 2) {
    TILE(tt,     0,     aF, bF, aG, bG)
    TILE(tt + 1, 65536, aG, bG, aF, bF)
  }
#undef TILE
#undef MFMA8
#undef STAGE_A
#undef STAGE_B

  // ---- epilogue: drain DMA, reuse LDS as a [256][256] bf16 C-tile ----
  asm volatile("s_waitcnt vmcnt(0)" ::: "memory");
  __syncthreads();
  {
    char* cb = lds;
    #pragma unroll
    for (int mf = 0; mf < 8; mf++)
      #pragma unroll
      for (int nf = 0; nf < 4; nf++)
        #pragma unroll
        for (int tt = 0; tt < 4; tt++) {
          int row = wm * 128 + mf * 16 + q * 4 + tt;
          int col = wn * 64 + nf * 16 + rr;
          int cs  = col ^ (((row >> 2) & 3) << 4);   // bank-spread q-groups
          *(bf16*)(cb + row * 512 + cs * 2) = (bf16)acc[mf][nf][tt];
        }
  }
  __syncthreads();
  {
    const char* cb = lds;
    #pragma unroll
    for (int i = 0; i < 16; i++) {
      int chunk = i * 512 + tid;          // 8192 chunks of 16 B
      int row = chunk >> 5, cc = chunk & 31;
      int cs  = cc ^ (((row >> 2) & 3) << 1);        // inverse of write swizzle
      bf16x8 v = *(const bf16x8*)(cb + (row * 32 + cs) * 16);
      *(bf16x8*)(C + (size_t)(bm * 256 + row) * N + bn * 256 + cc * 8) = v;
    }
  }
}

// ---------------- launch ----------------

extern "C" void kernel_launch(void* const* d_in, const int* in_sizes, int n_in,
                              void* d_out, int out_size, void* d_ws, size_t ws_size,
                              hipStream_t stream) {
  const float* x      = (const float*)d_in[0];
  const float* norm_w = (const float*)d_in[1];
  const float* w      = (const float*)d_in[2];

  float* out   = (float*)d_out;
  float* y4o   = out;
  float* s2o   = out + (size_t)NTOK * HID;           // y2_s [16384,16]
  float* s3o   = s2o + (size_t)NTOK * NGRP;          // y3_s [16384,16]

  char* ws = (char*)d_ws;
  const size_t WT_B = (size_t)3 * HID * HID * 2;     // 25,165,824
  const size_t AB_B = (size_t)NTOK * HID * 2;        // 67,108,864
  bf16* Wt   = (bf16*)ws;
  bf16* Abuf = (bf16*)(ws + WT_B);
  bf16* Cbuf = (bf16*)(ws + WT_B + AB_B);
  bf16* Rbuf = (bf16*)(ws + WT_B + 2 * AB_B);
  const size_t MATE = (size_t)HID * HID;

  dim3 gT(HID / 64, HID / 64, 3);
  int  gG = (NTOK / 256) * (HID / 256);    // 512 blocks; in-kernel XCD mapping

  k_transpose_cast<<<gT, 256, 0, stream>>>(w, Wt);
  k_pre<<<NTOK, 256, 0, stream>>>(x, norm_w, Abuf, Rbuf);
  k_gemm<<<gG, 512, 0, stream>>>(Abuf, Wt, Cbuf, NTOK, HID, HID);
  k_fuse_quant<<<NTOK, 256, 0, stream>>>(Rbuf, Cbuf, norm_w + HID, Rbuf, Abuf, s2o);
  k_gemm<<<gG, 512, 0, stream>>>(Abuf, Wt + MATE, Cbuf, NTOK, HID, HID);
  k_fuse_quant<<<NTOK, 256, 0, stream>>>(Rbuf, Cbuf, norm_w + 2 * HID, Rbuf, Abuf, s3o);
  k_gemm<<<gG, 512, 0, stream>>>(Abuf, Wt + 2 * MATE, Cbuf, NTOK, HID, HID);
  k_final<<<NTOK, 256, 0, stream>>>(Rbuf, Cbuf, norm_w + 3 * HID, y4o);
}